// Round 16
// baseline (280.187 us; speedup 1.0000x reference)
//
#include <hip/hip_runtime.h>
#include <hip/hip_bf16.h>

#define B_ 2
#define S_ 2048
#define D_ 1024
#define H_ 16
#define DK_ 64
#define FF_ 4096
#define M_ (B_ * S_)  // 4096 rows

typedef unsigned short u16;
typedef __bf16 bf16x8 __attribute__((ext_vector_type(8)));
typedef float f32x4 __attribute__((ext_vector_type(4)));
typedef u16 u16x4 __attribute__((ext_vector_type(4)));
typedef u16 u16x8 __attribute__((ext_vector_type(8)));

__device__ __forceinline__ u16 f2bf(float f) {
  __bf16 b = (__bf16)f;
  return __builtin_bit_cast(u16, b);
}
__device__ __forceinline__ float bf2f(u16 u) {
  __bf16 b = __builtin_bit_cast(__bf16, u);
  return (float)b;
}

// async global->LDS, 16B per lane. LDS dest is wave-uniform base + lane*16.
__device__ __forceinline__ void async_lds16(const void* g, void* l) {
  __builtin_amdgcn_global_load_lds(
      (const __attribute__((address_space(1))) unsigned int*)g,
      (__attribute__((address_space(3))) unsigned int*)l, 16, 0, 0);
}

// raw barrier + counted vmcnt (T4): keep prefetch loads in flight across
// barriers instead of __syncthreads' vmcnt(0)+lgkmcnt(0) drain.
__device__ __forceinline__ void raw_barrier() {
  asm volatile("s_barrier" ::: "memory");
}
#define VMCNT_WAIT(n) asm volatile("s_waitcnt vmcnt(" #n ")" ::: "memory")

// ---------------------------------------------------------------------------
// All weights f32 -> bf16 in ONE dispatch. W1/W3 are 16-ROW-BLOCK interleaved
// into wb13 (fused FF GEMM: j-even frags = a, j-odd = gate, same lane).
__global__ __launch_bounds__(256) void f2b_all(
    const float* __restrict__ wq, const float* __restrict__ wk,
    const float* __restrict__ wv, const float* __restrict__ wo,
    const float* __restrict__ w1, const float* __restrict__ w2,
    const float* __restrict__ w3, u16* __restrict__ wqkvb,
    u16* __restrict__ wob, u16* __restrict__ wb13, u16* __restrict__ w2b) {
  int i4 = blockIdx.x * 256 + threadIdx.x;  // < 4M float4s
  const float* src;
  u16* dst;
  int off, oo;
  if (i4 < 262144) { src = wq; dst = wqkvb; off = i4; oo = off; }
  else if (i4 < 524288) { src = wk; dst = wqkvb + 1048576; off = i4 - 262144; oo = off; }
  else if (i4 < 786432) { src = wv; dst = wqkvb + 2097152; off = i4 - 524288; oo = off; }
  else if (i4 < 1048576) { src = wo; dst = wob; off = i4 - 786432; oo = off; }
  else if (i4 < 2097152) {  // w1 row r -> wb13 row (r>>4)*32 + (r&15)
    src = w1; dst = wb13; off = i4 - 1048576;
    const int r = off >> 8;
    oo = (((r >> 4) * 32) + (r & 15)) * 256 + (off & 255);
  } else if (i4 < 3145728) { src = w2; dst = w2b; off = i4 - 2097152; oo = off; }
  else {  // w3 row r -> wb13 row (r>>4)*32 + 16 + (r&15)
    src = w3; dst = wb13; off = i4 - 3145728;
    const int r = off >> 8;
    oo = (((r >> 4) * 32) + 16 + (r & 15)) * 256 + (off & 255);
  }
  float4 v = ((const float4*)src)[off];
  u16x4 o;
  o[0] = f2bf(v.x); o[1] = f2bf(v.y); o[2] = f2bf(v.z); o[3] = f2bf(v.w);
  *(u16x4*)(dst + (size_t)oo * 4) = o;
}

// ---------------------------------------------------------------------------
// RMSNorm: f32 [rows][1024] -> bf16, block per row, 256 threads * 4 cols
__global__ __launch_bounds__(256) void rmsnorm_k(const float* __restrict__ X,
                                                 const float* __restrict__ G,
                                                 u16* __restrict__ Out) {
  const int row = blockIdx.x, tid = threadIdx.x;
  const float4 xv = *(const float4*)(X + (size_t)row * D_ + tid * 4);
  float ss = xv.x * xv.x + xv.y * xv.y + xv.z * xv.z + xv.w * xv.w;
#pragma unroll
  for (int off = 1; off < 64; off <<= 1) ss += __shfl_xor(ss, off);
  __shared__ float red[4];
  if ((tid & 63) == 0) red[tid >> 6] = ss;
  __syncthreads();
  const float tot = red[0] + red[1] + red[2] + red[3];
  const float sc = rsqrtf(tot * (1.0f / D_) + 1e-5f);
  const float4 gv = *(const float4*)(G + tid * 4);
  u16x4 o;
  o[0] = f2bf(xv.x * sc * gv.x);
  o[1] = f2bf(xv.y * sc * gv.y);
  o[2] = f2bf(xv.z * sc * gv.z);
  o[3] = f2bf(xv.w * sc * gv.w);
  *(u16x4*)(Out + (size_t)row * D_ + tid * 4) = o;
}

// ---------------------------------------------------------------------------
// 2D XCD-region block mapping: each XCD (= id&7) owns a rectangular RGN x RGM
// tile region, so its A panels and B panels stay L2-resident.
// Requires nwg == 8*RGN*RGM, gx % RGN == 0.
template <int RGN, int RGM>
__device__ __forceinline__ void region_map(int id, int gx, int BM, int BN,
                                           int& m0, int& n0) {
  const int xcd = id & 7, j = id >> 3;
  const int rcols = gx / RGN;
  m0 = ((xcd / rcols) * RGM + j / RGN) * BM;
  n0 = ((xcd % rcols) * RGN + (j % RGN)) * BN;
}

// ---------------------------------------------------------------------------
// 8-phase-style 256xBN x64 GEMM with NEVER-DRAIN 2-tile-ahead prefetch:
// 512 threads = 8 waves (2M x 4N), wave tile 128x(BN/4), LDS dbuf.
// buffer(t) is freed by the post-ph3 barrier of tile t -> STAGE(buf(t), t+2)
// there; the tile-top wait for t+1's loads is vmcnt(NL) on loads issued a
// FULL TILE earlier -> never vmcnt(0) in the main loop (T4 invariant).
// Safety: (a) STAGE(t+2) overwrites buf(t) only after all waves' ds_reads of
// buf(t) are register-consumed (pre-ph3 barrier orders them) and the post-ph3
// barrier is crossed; (b) reads of buf(t+1) gated by vmcnt(NL)+barrier where
// each wave's only NL outstanding loads are its own t+2 ones.
// EPI 0: bf16 store.
// EPI 3: fused QKV: Q,K RoPE via __shfl_xor pair rotation with INLINE
//        __sinf/__cosf (r7: pointer-output sincosf spills all acc VGPRs);
//        Q scaled 1/8; V stored transposed into Vt[32 bh][64 dk][2048 s].
// EPI 4: fused SwiGLU (16-row-block-interleaved wb13, per-lane, no shfl).
template <int EPI, int BN, int RGN, int RGM>
__global__ __launch_bounds__(512) void gemm8ph(const u16* __restrict__ A,
                                               const u16* __restrict__ Bw,
                                               void* __restrict__ Cout,
                                               const void* __restrict__ auxp,
                                               int N, int K,
                                               const int* __restrict__ tp) {
  constexpr int BM = 256, BK = 64;
  constexpr int CPR = BK / 8;          // 8 chunks per row
  constexpr int ACH = BM * CPR;        // 2048 A-chunks per K-tile
  constexpr int TCH = (BM + BN) * CPR; // total chunks per K-tile
  constexpr int NL = TCH / 512;        // loads per thread per K-tile
  constexpr int NR = BN / 64;          // B fragments per wave per kk
  static_assert(NL == 7 || NL == 8, "vmcnt literal dispatch below");
  __shared__ __align__(16) u16 As[2][BM * BK];
  __shared__ __align__(16) u16 Bs[2][BN * BK];
  const int tid = threadIdx.x, l = tid & 63, w = tid >> 6;
  const int gx = gridDim.x;
  const int id = blockIdx.y * gx + blockIdx.x;
  int m0, n0;
  region_map<RGN, RGM>(id, gx, BM, BN, m0, n0);
  const int wm = (w >> 2) * 128, wn = (w & 3) * (BN / 4);
  const int lr = l & 15, lg = l >> 4;

  f32x4 acc[8][NR] = {};

  auto STAGE_ALL = [&](int bf, int k0) {
#pragma unroll
    for (int i = 0; i < NL; ++i) {
      const int s = i * 512 + tid;
      const int base = i * 512 + w * 64;
      if (base < ACH) {
        const int r = s / CPR, ch = s % CPR;
        async_lds16(A + (size_t)(m0 + r) * K + k0 + ((ch ^ (r & 7)) * 8),
                    (char*)As[bf] + base * 16);
      } else {
        const int s2 = s - ACH;
        const int r = s2 / CPR, ch = s2 % CPR;
        async_lds16(Bw + (size_t)(n0 + r) * K + k0 + ((ch ^ (r & 7)) * 8),
                    (char*)Bs[bf] + (base - ACH) * 16);
      }
    }
  };

  auto WAIT_NL = [&]() {
    if constexpr (NL == 8) VMCNT_WAIT(8); else VMCNT_WAIT(7);
  };

  // prologue: stage tiles 0 and 1; wait for tile 0 only (tile 1 in flight)
  STAGE_ALL(0, 0);
  if (K > BK) {
    STAGE_ALL(1, BK);
    WAIT_NL();
  } else {
    VMCNT_WAIT(0);
  }
  raw_barrier();
  int cur = 0;
  for (int k0 = 0; k0 < K; k0 += BK) {
    bf16x8 bfr[NR];
#pragma unroll
    for (int ph = 0; ph < 4; ++ph) {
      const int kk = ph >> 1, iq = ph & 1;
      if (iq == 0) {  // B-half read once per kk, reused by both i-quads
#pragma unroll
        for (int j = 0; j < NR; ++j) {
          const int row = wn + j * 16 + lr;
          bfr[j] = *(const bf16x8*)&Bs[cur][row * BK +
                                            (((kk * 4 + lg) ^ (row & 7)) * 8)];
        }
      }
      bf16x8 af[4];
#pragma unroll
      for (int i = 0; i < 4; ++i) {
        const int row = wm + (iq * 4 + i) * 16 + lr;
        af[i] = *(const bf16x8*)&As[cur][row * BK +
                                         (((kk * 4 + lg) ^ (row & 7)) * 8)];
      }
      raw_barrier();
      __builtin_amdgcn_s_setprio(1);
#pragma unroll
      for (int i = 0; i < 4; ++i)
#pragma unroll
        for (int j = 0; j < NR; ++j)
          acc[iq * 4 + i][j] = __builtin_amdgcn_mfma_f32_16x16x32_bf16(
              af[i], bfr[j], acc[iq * 4 + i][j], 0, 0, 0);
      __builtin_amdgcn_s_setprio(0);
      if (ph < 3) raw_barrier();
    }
    raw_barrier();  // all waves done reading buf cur -> it's free
    if (k0 + 2 * BK < K) STAGE_ALL(cur, k0 + 2 * BK);  // prefetch t+2
    if (k0 + BK < K) {
      if (k0 + 2 * BK < K) WAIT_NL(); else VMCNT_WAIT(0);
      raw_barrier();  // tile t+1 (staged a full tile ago) visible to all
    }
    cur ^= 1;
  }

  // epilogue: C/D layout col = l&15, row = (l>>4)*4 + t  [m89-verified]
  if (EPI == 0 || EPI == 4) {
#pragma unroll
    for (int i = 0; i < 8; ++i) {
#pragma unroll
      for (int j = 0; j < NR; ++j) {
#pragma unroll
        for (int t = 0; t < 4; ++t) {
          const int grow = m0 + wm + i * 16 + lg * 4 + t;
          const int gcol = n0 + wn + j * 16 + lr;
          const float v = acc[i][j][t];
          if (EPI == 0) {
            ((u16*)Cout)[(size_t)grow * N + gcol] = f2bf(v);
          } else {
            if (j & 1) continue;  // handled with pair j, j+1
            const float a = v, g = acc[i][j + 1][t];
            const float sw = a / (1.f + __expf(-a)) * g;
            const int ocol = ((n0 + wn) >> 1) + (j >> 1) * 16 + lr;
            ((u16*)Cout)[(size_t)grow * FF_ + ocol] = f2bf(sw);
          }
        }
      }
    }
  } else {  // EPI 3: QKV + RoPE + V-transpose. Region per j (16-col runs
            // never straddle a 1024 boundary).
#pragma unroll
    for (int i = 0; i < 8; ++i) {
      const int grow0 = m0 + wm + i * 16 + lg * 4;
      float posf[4];
#pragma unroll
      for (int t = 0; t < 4; ++t) posf[t] = (float)tp[grow0 + t];
      const int bb = grow0 >> 11, s0 = grow0 & 2047;
#pragma unroll
      for (int j = 0; j < NR; ++j) {
        const int gcol = n0 + wn + j * 16 + lr;
        const int region = gcol >> 10;  // wave-uniform within this j
        if (region < 2) {
          u16* dst = (u16*)Cout + (size_t)region * ((size_t)M_ * D_);
          const float qscale = (region == 0) ? 0.125f : 1.0f;
          const float invf = __expf(-(float)((gcol & 63) >> 1) *
                                    (9.210340371976184f / 32.0f));
          const float sgn = (gcol & 1) ? 1.f : -1.f;
#pragma unroll
          for (int t = 0; t < 4; ++t) {
            const float own = acc[i][j][t];
            const float pe = __shfl_xor(own, 1);
            const float ang = posf[t] * invf;
            const float sn = __sinf(ang), cs = __cosf(ang);
            dst[(size_t)(grow0 + t) * D_ + (gcol & 1023)] =
                f2bf((own * cs + sgn * pe * sn) * qscale);
          }
        } else {
          u16* vt = (u16*)Cout + 2 * ((size_t)M_ * D_);
          const int vcol = gcol & 1023;
          u16x4 pk;
#pragma unroll
          for (int t = 0; t < 4; ++t) pk[t] = f2bf(acc[i][j][t]);
          const size_t addr =
              ((size_t)(bb * 16 + (vcol >> 6)) * 64 + (vcol & 63)) * 2048 + s0;
          *(u16x4*)(vt + addr) = pk;
        }
      }
    }
  }
}

// ---------------------------------------------------------------------------
// 2-phase double-buffered GEMM with counted-vmcnt barriers (r9-proven), used
// for the N=1024 shapes (WO, W2) at 128x128 BK=128. EPI 1: f32 aux+acc store.
// NOTE: no libm calls with pointer outs (sincosf) in epilogues (r7 postmortem).
template <int BM, int BN, int BK, int EPI, int RGN, int RGM>
__global__ __launch_bounds__(512) void gemm2ph(const u16* __restrict__ A,
                                               const u16* __restrict__ Bw,
                                               void* __restrict__ Cout,
                                               const void* __restrict__ auxp,
                                               int N, int K) {
  constexpr int CPR = BK / 8;
  constexpr int ACH = BM * CPR;
  constexpr int TCH = (BM + BN) * CPR;
  constexpr int MR = BM / 32, NR = BN / 64;
  static_assert(TCH / 512 == 8, "vmcnt(8) assumes 8 loads/thread per STAGE");
  __shared__ __align__(16) u16 As[2][BM * BK];
  __shared__ __align__(16) u16 Bs[2][BN * BK];
  const int tid = threadIdx.x, l = tid & 63, w = tid >> 6;
  const int gx = gridDim.x;
  const int id = blockIdx.y * gx + blockIdx.x;
  int m0, n0;
  region_map<RGN, RGM>(id, gx, BM, BN, m0, n0);
  const int wm = (w >> 2) * (BM / 2), wn = (w & 3) * (BN / 4);
  const int lr = l & 15, lg = l >> 4;

  f32x4 acc[MR][NR] = {};

  auto STAGE = [&](int bf, int k0) {
#pragma unroll
    for (int i = 0; i < TCH / 512; ++i) {
      const int s = i * 512 + tid;
      const int base = i * 512 + w * 64;
      if (base < ACH) {
        const int r = s / CPR, ch = s % CPR;
        async_lds16(A + (size_t)(m0 + r) * K + k0 + ((ch ^ (r & 7)) * 8),
                    (char*)As[bf] + base * 16);
      } else {
        const int s2 = s - ACH;
        const int r = s2 / CPR, ch = s2 % CPR;
        async_lds16(Bw + (size_t)(n0 + r) * K + k0 + ((ch ^ (r & 7)) * 8),
                    (char*)Bs[bf] + (base - ACH) * 16);
      }
    }
  };

  STAGE(0, 0);
  int cur = 0;
  for (int k0 = 0; k0 < K; k0 += BK) {
    if (k0 + BK < K) {
      STAGE(cur ^ 1, k0 + BK);
      VMCNT_WAIT(8);
    } else {
      VMCNT_WAIT(0);
    }
    raw_barrier();
#pragma unroll
    for (int kk = 0; kk < BK / 32; ++kk) {
      bf16x8 af[MR], bfr[NR];
#pragma unroll
      for (int i = 0; i < MR; ++i) {
        const int row = wm + i * 16 + lr;
        af[i] = *(const bf16x8*)&As[cur][row * BK +
                                         (((kk * 4 + lg) ^ (row & 7)) * 8)];
      }
#pragma unroll
      for (int j = 0; j < NR; ++j) {
        const int row = wn + j * 16 + lr;
        bfr[j] = *(const bf16x8*)&Bs[cur][row * BK +
                                          (((kk * 4 + lg) ^ (row & 7)) * 8)];
      }
      __builtin_amdgcn_s_setprio(1);
#pragma unroll
      for (int i = 0; i < MR; ++i)
#pragma unroll
        for (int j = 0; j < NR; ++j)
          acc[i][j] = __builtin_amdgcn_mfma_f32_16x16x32_bf16(
              af[i], bfr[j], acc[i][j], 0, 0, 0);
      __builtin_amdgcn_s_setprio(0);
    }
    raw_barrier();
    cur ^= 1;
  }

#pragma unroll
  for (int i = 0; i < MR; ++i) {
#pragma unroll
    for (int j = 0; j < NR; ++j) {
#pragma unroll
      for (int t = 0; t < 4; ++t) {
        const int grow = m0 + wm + i * 16 + lg * 4 + t;
        const int gcol = n0 + wn + j * 16 + lr;
        const float v = acc[i][j][t];
        if (EPI == 0) {
          ((u16*)Cout)[(size_t)grow * N + gcol] = f2bf(v);
        } else if (EPI == 1) {
          const size_t idx = (size_t)grow * N + gcol;
          ((float*)Cout)[idx] = ((const float*)auxp)[idx] + v;
        }
      }
    }
  }
}

// ---------------------------------------------------------------------------
// Causal flash attention. Q pre-scaled by 1/8. 1024 blocks (XCD-chunked,
// heavy-first), 4 waves x 16 q-rows, KVBLK=64, dbuf LDS, XOR-swizzled K/V
// AND P (40KB LDS total -> 4 blocks/CU), full/diag tile split, defer-max
// (THR=8), row-sum via ones-MFMA, counted-vmcnt loop (T4).
__global__ __launch_bounds__(256) void attn_fwd(const u16* __restrict__ Q,
                                                const u16* __restrict__ K,
                                                const u16* __restrict__ Vt,
                                                u16* __restrict__ O) {
  __shared__ __align__(16) u16 Ks[2][64 * 64];
  __shared__ __align__(16) u16 Vs[2][64 * 64];
  __shared__ __align__(16) u16 Ps[4][16 * 64];  // XOR-swizzled, 8KB
  const int tid = threadIdx.x, l = tid & 63, w = tid >> 6;
  const int lr = l & 15, lg = l >> 4;
  const int bid = blockIdx.x;
  const int xcd = bid & 7, i = bid >> 3;  // i in [0,128)
  const int bh = xcd * 4 + (i >> 5);      // 4 heads per XCD
  const int qx = 31 - (i & 31);           // heavy first
  const int b = bh >> 4, h = bh & 15;
  const int q0w = qx * 64 + w * 16;

  const u16* Kb = K + (size_t)(b * S_) * D_ + h * DK_;
  const u16* Vb = Vt + (size_t)bh * DK_ * S_;

  bf16x8 aq[2];
  {
    const u16* qp = Q + (size_t)(b * S_ + q0w + lr) * D_ + h * DK_ + lg * 8;
    aq[0] = *(const bf16x8*)qp;
    aq[1] = *(const bf16x8*)(qp + 32);
  }
  f32x4 oacc[4] = {};
  float mrow[4], lrow[4];
#pragma unroll
  for (int t = 0; t < 4; ++t) { mrow[t] = -1e30f; lrow[t] = 0.f; }

  u16x8 ones_u;
#pragma unroll
  for (int j = 0; j < 8; ++j) ones_u[j] = 0x3F80;  // bf16 1.0
  const bf16x8 ones = __builtin_bit_cast(bf16x8, ones_u);

  const int ntiles = qx + 1;

  auto STAGE = [&](int bf, int t) {
#pragma unroll
    for (int inst = 0; inst < 2; ++inst) {
      const int s = (w * 2 + inst) * 64 + l;
      const int r = s >> 3, ch = s & 7;
      const int chs = ch ^ (r & 7);
      async_lds16(Kb + (size_t)(t * 64 + r) * D_ + chs * 8,
                  (char*)Ks[bf] + (w * 2 + inst) * 1024);
      async_lds16(Vb + (size_t)r * S_ + t * 64 + chs * 8,
                  (char*)Vs[bf] + (w * 2 + inst) * 1024);
    }
  };

  // P store: row r, col c (orig) -> Ps[w][r*64 + (c ^ ((r&7)*8))]
  auto PSTORE = [&](int r, int c, u16 v) {
    Ps[w][r * 64 + (c ^ ((r & 7) * 8))] = v;
  };

  STAGE(0, 0);
  int cur = 0;
  for (int it = 0; it < ntiles; ++it) {
    if (it + 1 < ntiles) {
      STAGE(cur ^ 1, it + 1);
      VMCNT_WAIT(4);  // tile-cur loads landed; next tile's 4 in flight
    } else {
      VMCNT_WAIT(0);
    }
    raw_barrier();
    // QK^T: S[16q][64kv]
    f32x4 sf[4];
    __builtin_amdgcn_s_setprio(1);
#pragma unroll
    for (int n = 0; n < 4; ++n) {
      const int kvr = n * 16 + lr;
      f32x4 z = {};
      bf16x8 bk0 = *(const bf16x8*)&Ks[cur][kvr * 64 + ((lg ^ (kvr & 7)) * 8)];
      bf16x8 bk1 =
          *(const bf16x8*)&Ks[cur][kvr * 64 + (((4 + lg) ^ (kvr & 7)) * 8)];
      z = __builtin_amdgcn_mfma_f32_16x16x32_bf16(aq[0], bk0, z, 0, 0, 0);
      z = __builtin_amdgcn_mfma_f32_16x16x32_bf16(aq[1], bk1, z, 0, 0, 0);
      sf[n] = z;
    }
    __builtin_amdgcn_s_setprio(0);
    if (it < qx) {  // FULL tile: no mask; defer-max
      float fm[4];
      bool exc = false;
#pragma unroll
      for (int t = 0; t < 4; ++t) {
        fm[t] = fmaxf(fmaxf(sf[0][t], sf[1][t]), fmaxf(sf[2][t], sf[3][t]));
        exc |= fm[t] > mrow[t] + 8.f;
      }
      if (__any(exc)) {
#pragma unroll
        for (int t = 0; t < 4; ++t) {
          float mx = fm[t];
#pragma unroll
          for (int off = 1; off < 16; off <<= 1)
            mx = fmaxf(mx, __shfl_xor(mx, off));
          const float nm = fmaxf(mrow[t], mx);
          const float c = __expf(mrow[t] - nm);
          mrow[t] = nm;
          lrow[t] *= c;
#pragma unroll
          for (int d = 0; d < 4; ++d) oacc[d][t] *= c;
        }
      }
#pragma unroll
      for (int t = 0; t < 4; ++t)
#pragma unroll
        for (int n = 0; n < 4; ++n)
          PSTORE(lg * 4 + t, n * 16 + lr, f2bf(__expf(sf[n][t] - mrow[t])));
    } else {  // DIAGONAL tile: causal mask + full reduce
      const int kv0 = it * 64;
#pragma unroll
      for (int t = 0; t < 4; ++t) {
        const int qrow = q0w + lg * 4 + t;
        float v[4];
#pragma unroll
        for (int n = 0; n < 4; ++n)
          v[n] = (kv0 + n * 16 + lr <= qrow) ? sf[n][t] : -1e30f;
        float mx = fmaxf(fmaxf(v[0], v[1]), fmaxf(v[2], v[3]));
#pragma unroll
        for (int off = 1; off < 16; off <<= 1)
          mx = fmaxf(mx, __shfl_xor(mx, off));
        const float nm = fmaxf(mrow[t], mx);
        const float c = __expf(mrow[t] - nm);
        mrow[t] = nm;
        lrow[t] *= c;
#pragma unroll
        for (int d = 0; d < 4; ++d) oacc[d][t] *= c;
#pragma unroll
        for (int n = 0; n < 4; ++n)
          PSTORE(lg * 4 + t, n * 16 + lr, f2bf(__expf(v[n] - nm)));
      }
    }
    // PV + row-sum (ones-MFMA). A-frag read: row lr, orig cols lg*8 / 32+lg*8
    bf16x8 ap0 = *(const bf16x8*)&Ps[w][lr * 64 + ((lg ^ (lr & 7)) * 8)];
    bf16x8 ap1 =
        *(const bf16x8*)&Ps[w][lr * 64 + (((4 + lg) ^ (lr & 7)) * 8)];
    __builtin_amdgcn_s_setprio(1);
    f32x4 zs = {};
    zs = __builtin_amdgcn_mfma_f32_16x16x32_bf16(ap0, ones, zs, 0, 0, 0);
    zs = __builtin_amdgcn_mfma_f32_16x16x32_bf16(ap1, ones, zs, 0, 0, 0);
#pragma unroll
    for (int d = 0; d < 4; ++d) {
      const int row = d * 16 + lr;
      bf16x8 bv0 = *(const bf16x8*)&Vs[cur][row * 64 + ((lg ^ (row & 7)) * 8)];
      bf16x8 bv1 =
          *(const bf16x8*)&Vs[cur][row * 64 + (((4 + lg) ^ (row & 7)) * 8)];
      oacc[d] = __builtin_amdgcn_mfma_f32_16x16x32_bf16(ap0, bv0, oacc[d], 0, 0, 0);
      oacc[d] = __builtin_amdgcn_mfma_f32_16x16x32_bf16(ap1, bv1, oacc[d], 0, 0, 0);
    }
    __builtin_amdgcn_s_setprio(0);
#pragma unroll
    for (int t = 0; t < 4; ++t) lrow[t] += zs[t];
    raw_barrier();  // compute done before next STAGE overwrites buf cur
    cur ^= 1;
  }
#pragma unroll
  for (int d = 0; d < 4; ++d) {
#pragma unroll
    for (int t = 0; t < 4; ++t) {
      const size_t idx =
          (size_t)(b * S_ + q0w + lg * 4 + t) * D_ + h * DK_ + d * 16 + lr;
      O[idx] = f2bf(oacc[d][t] / lrow[t]);
    }
  }
}

// ---------------------------------------------------------------------------
extern "C" void kernel_launch(void* const* d_in, const int* in_sizes, int n_in,
                              void* d_out, int out_size, void* d_ws,
                              size_t ws_size, hipStream_t stream) {
  (void)in_sizes; (void)n_in; (void)out_size; (void)ws_size;
  const float* x = (const float*)d_in[0];
  const float* wq = (const float*)d_in[1];
  const float* wk = (const float*)d_in[2];
  const float* wv = (const float*)d_in[3];
  const float* wo = (const float*)d_in[4];
  const float* w1 = (const float*)d_in[5];
  const float* w2 = (const float*)d_in[6];
  const float* w3 = (const float*)d_in[7];
  const float* g1 = (const float*)d_in[8];
  const float* g2 = (const float*)d_in[9];
  const int* tp = (const int*)d_in[10];
  float* out = (float*)d_out;

  char* ws = (char*)d_ws;
  const size_t MB = 1024u * 1024u;
  u16* wqkvb = (u16*)(ws + 0 * MB);   // [3072][1024] = 6MB
  u16* wob  = (u16*)(ws + 6 * MB);
  u16* wb13 = (u16*)(ws + 8 * MB);    // [8192][1024] block-interleaved = 16MB
  u16* w2b  = (u16*)(ws + 24 * MB);   // [1024][4096] = 8MB
  u16* hb   = (u16*)(ws + 32 * MB);   // rmsnorm1 out; later attn-out
  float* yb = (float*)(ws + 40 * MB); // 16MB f32
  u16* h2b  = (u16*)(ws + 56 * MB);
  u16* Qb   = (u16*)(ws + 64 * MB);   // Q; K at +8MB; Vt at +16MB (EPI3)
  u16* Kb   = (u16*)(ws + 72 * MB);
  u16* Vtb  = (u16*)(ws + 80 * MB);
  u16* ffb  = (u16*)(ws + 96 * MB);   // [4096][4096] = 32MB
  u16* aob  = hb;

  f2b_all<<<16384, 256, 0, stream>>>(wq, wk, wv, wo, w1, w2, w3, wqkvb, wob,
                                     wb13, w2b);

  rmsnorm_k<<<4096, 256, 0, stream>>>(x, g1, hb);

  // fused QKV projection + RoPE + V-transpose: N=3072, BN=192 -> 256 blocks,
  // regions 4n x 8m per XCD
  gemm8ph<3, 192, 4, 8><<<dim3(16, 16), 512, 0, stream>>>(
      hb, wqkvb, Qb, nullptr, 3072, 1024, tp);

  attn_fwd<<<1024, 256, 0, stream>>>(Qb, Kb, Vtb, aob);

  // WO: 128^2 tiles, BK=128, regions 4n x 8m per XCD
  gemm2ph<128, 128, 128, 1, 4, 8><<<dim3(8, 32), 512, 0, stream>>>(
      aob, wob, yb, x, 1024, 1024);
  rmsnorm_k<<<4096, 256, 0, stream>>>(yb, g2, h2b);

  // fused FF up-projection + SwiGLU: N=8192, regions 8n x 8m per XCD
  gemm8ph<4, 256, 8, 8><<<dim3(32, 16), 512, 0, stream>>>(
      h2b, wb13, ffb, nullptr, 8192, 1024, nullptr);
  // W2: 128^2 tiles, BK=128, regions 4n x 8m per XCD
  gemm2ph<128, 128, 128, 1, 4, 8><<<dim3(8, 32), 512, 0, stream>>>(
      ffb, w2b, out, yb, 1024, 4096);
}

// Round 17
// 270.716 us; speedup vs baseline: 1.0350x; 1.0350x over previous
//
#include <hip/hip_runtime.h>
#include <hip/hip_bf16.h>

#define B_ 2
#define S_ 2048
#define D_ 1024
#define H_ 16
#define DK_ 64
#define FF_ 4096
#define M_ (B_ * S_)  // 4096 rows

typedef unsigned short u16;
typedef __bf16 bf16x8 __attribute__((ext_vector_type(8)));
typedef float f32x4 __attribute__((ext_vector_type(4)));
typedef u16 u16x4 __attribute__((ext_vector_type(4)));
typedef u16 u16x8 __attribute__((ext_vector_type(8)));

__device__ __forceinline__ u16 f2bf(float f) {
  __bf16 b = (__bf16)f;
  return __builtin_bit_cast(u16, b);
}
__device__ __forceinline__ float bf2f(u16 u) {
  __bf16 b = __builtin_bit_cast(__bf16, u);
  return (float)b;
}

// async global->LDS, 16B per lane. LDS dest is wave-uniform base + lane*16.
__device__ __forceinline__ void async_lds16(const void* g, void* l) {
  __builtin_amdgcn_global_load_lds(
      (const __attribute__((address_space(1))) unsigned int*)g,
      (__attribute__((address_space(3))) unsigned int*)l, 16, 0, 0);
}

// raw barrier + counted vmcnt (T4): keep prefetch loads in flight across
// barriers instead of __syncthreads' vmcnt(0)+lgkmcnt(0) drain.
__device__ __forceinline__ void raw_barrier() {
  asm volatile("s_barrier" ::: "memory");
}
#define VMCNT_WAIT(n) asm volatile("s_waitcnt vmcnt(" #n ")" ::: "memory")

// ---------------------------------------------------------------------------
// All weights f32 -> bf16 in ONE dispatch. W1/W3 are 16-ROW-BLOCK interleaved
// into wb13 (fused FF GEMM: j-even frags = a, j-odd = gate, same lane).
__global__ __launch_bounds__(256) void f2b_all(
    const float* __restrict__ wq, const float* __restrict__ wk,
    const float* __restrict__ wv, const float* __restrict__ wo,
    const float* __restrict__ w1, const float* __restrict__ w2,
    const float* __restrict__ w3, u16* __restrict__ wqkvb,
    u16* __restrict__ wob, u16* __restrict__ wb13, u16* __restrict__ w2b) {
  int i4 = blockIdx.x * 256 + threadIdx.x;  // < 4M float4s
  const float* src;
  u16* dst;
  int off, oo;
  if (i4 < 262144) { src = wq; dst = wqkvb; off = i4; oo = off; }
  else if (i4 < 524288) { src = wk; dst = wqkvb + 1048576; off = i4 - 262144; oo = off; }
  else if (i4 < 786432) { src = wv; dst = wqkvb + 2097152; off = i4 - 524288; oo = off; }
  else if (i4 < 1048576) { src = wo; dst = wob; off = i4 - 786432; oo = off; }
  else if (i4 < 2097152) {  // w1 row r -> wb13 row (r>>4)*32 + (r&15)
    src = w1; dst = wb13; off = i4 - 1048576;
    const int r = off >> 8;
    oo = (((r >> 4) * 32) + (r & 15)) * 256 + (off & 255);
  } else if (i4 < 3145728) { src = w2; dst = w2b; off = i4 - 2097152; oo = off; }
  else {  // w3 row r -> wb13 row (r>>4)*32 + 16 + (r&15)
    src = w3; dst = wb13; off = i4 - 3145728;
    const int r = off >> 8;
    oo = (((r >> 4) * 32) + 16 + (r & 15)) * 256 + (off & 255);
  }
  float4 v = ((const float4*)src)[off];
  u16x4 o;
  o[0] = f2bf(v.x); o[1] = f2bf(v.y); o[2] = f2bf(v.z); o[3] = f2bf(v.w);
  *(u16x4*)(dst + (size_t)oo * 4) = o;
}

// ---------------------------------------------------------------------------
// RMSNorm: f32 [rows][1024] -> bf16, block per row, 256 threads * 4 cols
__global__ __launch_bounds__(256) void rmsnorm_k(const float* __restrict__ X,
                                                 const float* __restrict__ G,
                                                 u16* __restrict__ Out) {
  const int row = blockIdx.x, tid = threadIdx.x;
  const float4 xv = *(const float4*)(X + (size_t)row * D_ + tid * 4);
  float ss = xv.x * xv.x + xv.y * xv.y + xv.z * xv.z + xv.w * xv.w;
#pragma unroll
  for (int off = 1; off < 64; off <<= 1) ss += __shfl_xor(ss, off);
  __shared__ float red[4];
  if ((tid & 63) == 0) red[tid >> 6] = ss;
  __syncthreads();
  const float tot = red[0] + red[1] + red[2] + red[3];
  const float sc = rsqrtf(tot * (1.0f / D_) + 1e-5f);
  const float4 gv = *(const float4*)(G + tid * 4);
  u16x4 o;
  o[0] = f2bf(xv.x * sc * gv.x);
  o[1] = f2bf(xv.y * sc * gv.y);
  o[2] = f2bf(xv.z * sc * gv.z);
  o[3] = f2bf(xv.w * sc * gv.w);
  *(u16x4*)(Out + (size_t)row * D_ + tid * 4) = o;
}

// ---------------------------------------------------------------------------
// 2D XCD-region block mapping: each XCD (= id&7) owns a rectangular RGN x RGM
// tile region, so its A panels and B panels stay L2-resident.
// Requires nwg == 8*RGN*RGM, gx % RGN == 0.
template <int RGN, int RGM>
__device__ __forceinline__ void region_map(int id, int gx, int BM, int BN,
                                           int& m0, int& n0) {
  const int xcd = id & 7, j = id >> 3;
  const int rcols = gx / RGN;
  m0 = ((xcd / rcols) * RGM + j / RGN) * BM;
  n0 = ((xcd % rcols) * RGN + (j % RGN)) * BN;
}

// ---------------------------------------------------------------------------
// 8-phase-style 256xBN x64 GEMM (r15-proven schedule: ALL prefetch loads
// issued in PHASE 0, overlapped with phase-0 ds_reads/MFMA; tile-top
// vmcnt(0) lands ~3.25 phases after issue -> mostly covered w/ region map.
// r16 lesson: issuing the prefetch burst at the tile boundary (between
// barriers, no compute in flight) exposes the issue cost serially -> slower).
// EPI 0: bf16 store.
// EPI 3: fused QKV: Q,K RoPE via __shfl_xor pair rotation with INLINE
//        __sinf/__cosf (r7: pointer-output sincosf spills all acc VGPRs);
//        Q scaled 1/8; V stored transposed into Vt[32 bh][64 dk][2048 s].
// EPI 4: fused SwiGLU (16-row-block-interleaved wb13, per-lane, no shfl).
template <int EPI, int BN, int RGN, int RGM>
__global__ __launch_bounds__(512) void gemm8ph(const u16* __restrict__ A,
                                               const u16* __restrict__ Bw,
                                               void* __restrict__ Cout,
                                               const void* __restrict__ auxp,
                                               int N, int K,
                                               const int* __restrict__ tp) {
  constexpr int BM = 256, BK = 64;
  constexpr int CPR = BK / 8;          // 8 chunks per row
  constexpr int ACH = BM * CPR;        // 2048 A-chunks per K-tile
  constexpr int TCH = (BM + BN) * CPR; // total chunks per K-tile
  constexpr int NL = TCH / 512;        // loads per thread per K-tile
  constexpr int NR = BN / 64;          // B fragments per wave per kk
  __shared__ __align__(16) u16 As[2][BM * BK];
  __shared__ __align__(16) u16 Bs[2][BN * BK];
  const int tid = threadIdx.x, l = tid & 63, w = tid >> 6;
  const int gx = gridDim.x;
  const int id = blockIdx.y * gx + blockIdx.x;
  int m0, n0;
  region_map<RGN, RGM>(id, gx, BM, BN, m0, n0);
  const int wm = (w >> 2) * 128, wn = (w & 3) * (BN / 4);
  const int lr = l & 15, lg = l >> 4;

  f32x4 acc[8][NR] = {};

  auto STAGE_ALL = [&](int bf, int k0) {
#pragma unroll
    for (int i = 0; i < NL; ++i) {
      const int s = i * 512 + tid;
      const int base = i * 512 + w * 64;
      if (base < ACH) {
        const int r = s / CPR, ch = s % CPR;
        async_lds16(A + (size_t)(m0 + r) * K + k0 + ((ch ^ (r & 7)) * 8),
                    (char*)As[bf] + base * 16);
      } else {
        const int s2 = s - ACH;
        const int r = s2 / CPR, ch = s2 % CPR;
        async_lds16(Bw + (size_t)(n0 + r) * K + k0 + ((ch ^ (r & 7)) * 8),
                    (char*)Bs[bf] + (base - ACH) * 16);
      }
    }
  };

  STAGE_ALL(0, 0);
  VMCNT_WAIT(0);
  raw_barrier();
  int cur = 0;
  for (int k0 = 0; k0 < K; k0 += BK) {
    const bool more = (k0 + BK) < K;
    bf16x8 bfr[NR];
#pragma unroll
    for (int ph = 0; ph < 4; ++ph) {
      const int kk = ph >> 1, iq = ph & 1;
      if (iq == 0) {  // B-half read once per kk, reused by both i-quads
#pragma unroll
        for (int j = 0; j < NR; ++j) {
          const int row = wn + j * 16 + lr;
          bfr[j] = *(const bf16x8*)&Bs[cur][row * BK +
                                            (((kk * 4 + lg) ^ (row & 7)) * 8)];
        }
      }
      bf16x8 af[4];
#pragma unroll
      for (int i = 0; i < 4; ++i) {
        const int row = wm + (iq * 4 + i) * 16 + lr;
        af[i] = *(const bf16x8*)&As[cur][row * BK +
                                         (((kk * 4 + lg) ^ (row & 7)) * 8)];
      }
      // all prefetch issued in phase 0 -> overlapped with compute issue
      if (more && ph == 0) STAGE_ALL(cur ^ 1, k0 + BK);
      raw_barrier();
      __builtin_amdgcn_s_setprio(1);
#pragma unroll
      for (int i = 0; i < 4; ++i)
#pragma unroll
        for (int j = 0; j < NR; ++j)
          acc[iq * 4 + i][j] = __builtin_amdgcn_mfma_f32_16x16x32_bf16(
              af[i], bfr[j], acc[iq * 4 + i][j], 0, 0, 0);
      __builtin_amdgcn_s_setprio(0);
      if (ph < 3) raw_barrier();
    }
    if (more) {
      VMCNT_WAIT(0);  // loads issued 3.25 phases ago; L2-hit w/ region map
      raw_barrier();  // serves as phase-3 trailing barrier
    }
    cur ^= 1;
  }

  // epilogue: C/D layout col = l&15, row = (l>>4)*4 + t  [m89-verified]
  if (EPI == 0 || EPI == 4) {
#pragma unroll
    for (int i = 0; i < 8; ++i) {
#pragma unroll
      for (int j = 0; j < NR; ++j) {
#pragma unroll
        for (int t = 0; t < 4; ++t) {
          const int grow = m0 + wm + i * 16 + lg * 4 + t;
          const int gcol = n0 + wn + j * 16 + lr;
          const float v = acc[i][j][t];
          if (EPI == 0) {
            ((u16*)Cout)[(size_t)grow * N + gcol] = f2bf(v);
          } else {
            if (j & 1) continue;  // handled with pair j, j+1
            const float a = v, g = acc[i][j + 1][t];
            const float sw = a / (1.f + __expf(-a)) * g;
            const int ocol = ((n0 + wn) >> 1) + (j >> 1) * 16 + lr;
            ((u16*)Cout)[(size_t)grow * FF_ + ocol] = f2bf(sw);
          }
        }
      }
    }
  } else {  // EPI 3: QKV + RoPE + V-transpose. Region per j (16-col runs
            // never straddle a 1024 boundary).
#pragma unroll
    for (int i = 0; i < 8; ++i) {
      const int grow0 = m0 + wm + i * 16 + lg * 4;
      float posf[4];
#pragma unroll
      for (int t = 0; t < 4; ++t) posf[t] = (float)tp[grow0 + t];
      const int bb = grow0 >> 11, s0 = grow0 & 2047;
#pragma unroll
      for (int j = 0; j < NR; ++j) {
        const int gcol = n0 + wn + j * 16 + lr;
        const int region = gcol >> 10;  // wave-uniform within this j
        if (region < 2) {
          u16* dst = (u16*)Cout + (size_t)region * ((size_t)M_ * D_);
          const float qscale = (region == 0) ? 0.125f : 1.0f;
          const float invf = __expf(-(float)((gcol & 63) >> 1) *
                                    (9.210340371976184f / 32.0f));
          const float sgn = (gcol & 1) ? 1.f : -1.f;
#pragma unroll
          for (int t = 0; t < 4; ++t) {
            const float own = acc[i][j][t];
            const float pe = __shfl_xor(own, 1);
            const float ang = posf[t] * invf;
            const float sn = __sinf(ang), cs = __cosf(ang);
            dst[(size_t)(grow0 + t) * D_ + (gcol & 1023)] =
                f2bf((own * cs + sgn * pe * sn) * qscale);
          }
        } else {
          u16* vt = (u16*)Cout + 2 * ((size_t)M_ * D_);
          const int vcol = gcol & 1023;
          u16x4 pk;
#pragma unroll
          for (int t = 0; t < 4; ++t) pk[t] = f2bf(acc[i][j][t]);
          const size_t addr =
              ((size_t)(bb * 16 + (vcol >> 6)) * 64 + (vcol & 63)) * 2048 + s0;
          *(u16x4*)(vt + addr) = pk;
        }
      }
    }
  }
}

// ---------------------------------------------------------------------------
// 2-phase double-buffered GEMM with counted-vmcnt barriers (r9-proven), used
// for the N=1024 shapes (WO, W2) at 128x128 BK=128. EPI 1: f32 aux+acc store.
// NOTE: no libm calls with pointer outs (sincosf) in epilogues (r7 postmortem).
template <int BM, int BN, int BK, int EPI, int RGN, int RGM>
__global__ __launch_bounds__(512) void gemm2ph(const u16* __restrict__ A,
                                               const u16* __restrict__ Bw,
                                               void* __restrict__ Cout,
                                               const void* __restrict__ auxp,
                                               int N, int K) {
  constexpr int CPR = BK / 8;
  constexpr int ACH = BM * CPR;
  constexpr int TCH = (BM + BN) * CPR;
  constexpr int MR = BM / 32, NR = BN / 64;
  static_assert(TCH / 512 == 8, "vmcnt(8) assumes 8 loads/thread per STAGE");
  __shared__ __align__(16) u16 As[2][BM * BK];
  __shared__ __align__(16) u16 Bs[2][BN * BK];
  const int tid = threadIdx.x, l = tid & 63, w = tid >> 6;
  const int gx = gridDim.x;
  const int id = blockIdx.y * gx + blockIdx.x;
  int m0, n0;
  region_map<RGN, RGM>(id, gx, BM, BN, m0, n0);
  const int wm = (w >> 2) * (BM / 2), wn = (w & 3) * (BN / 4);
  const int lr = l & 15, lg = l >> 4;

  f32x4 acc[MR][NR] = {};

  auto STAGE = [&](int bf, int k0) {
#pragma unroll
    for (int i = 0; i < TCH / 512; ++i) {
      const int s = i * 512 + tid;
      const int base = i * 512 + w * 64;
      if (base < ACH) {
        const int r = s / CPR, ch = s % CPR;
        async_lds16(A + (size_t)(m0 + r) * K + k0 + ((ch ^ (r & 7)) * 8),
                    (char*)As[bf] + base * 16);
      } else {
        const int s2 = s - ACH;
        const int r = s2 / CPR, ch = s2 % CPR;
        async_lds16(Bw + (size_t)(n0 + r) * K + k0 + ((ch ^ (r & 7)) * 8),
                    (char*)Bs[bf] + (base - ACH) * 16);
      }
    }
  };

  STAGE(0, 0);
  int cur = 0;
  for (int k0 = 0; k0 < K; k0 += BK) {
    if (k0 + BK < K) {
      STAGE(cur ^ 1, k0 + BK);
      VMCNT_WAIT(8);
    } else {
      VMCNT_WAIT(0);
    }
    raw_barrier();
#pragma unroll
    for (int kk = 0; kk < BK / 32; ++kk) {
      bf16x8 af[MR], bfr[NR];
#pragma unroll
      for (int i = 0; i < MR; ++i) {
        const int row = wm + i * 16 + lr;
        af[i] = *(const bf16x8*)&As[cur][row * BK +
                                         (((kk * 4 + lg) ^ (row & 7)) * 8)];
      }
#pragma unroll
      for (int j = 0; j < NR; ++j) {
        const int row = wn + j * 16 + lr;
        bfr[j] = *(const bf16x8*)&Bs[cur][row * BK +
                                          (((kk * 4 + lg) ^ (row & 7)) * 8)];
      }
      __builtin_amdgcn_s_setprio(1);
#pragma unroll
      for (int i = 0; i < MR; ++i)
#pragma unroll
        for (int j = 0; j < NR; ++j)
          acc[i][j] = __builtin_amdgcn_mfma_f32_16x16x32_bf16(
              af[i], bfr[j], acc[i][j], 0, 0, 0);
      __builtin_amdgcn_s_setprio(0);
    }
    raw_barrier();
    cur ^= 1;
  }

#pragma unroll
  for (int i = 0; i < MR; ++i) {
#pragma unroll
    for (int j = 0; j < NR; ++j) {
#pragma unroll
      for (int t = 0; t < 4; ++t) {
        const int grow = m0 + wm + i * 16 + lg * 4 + t;
        const int gcol = n0 + wn + j * 16 + lr;
        const float v = acc[i][j][t];
        if (EPI == 0) {
          ((u16*)Cout)[(size_t)grow * N + gcol] = f2bf(v);
        } else if (EPI == 1) {
          const size_t idx = (size_t)grow * N + gcol;
          ((float*)Cout)[idx] = ((const float*)auxp)[idx] + v;
        }
      }
    }
  }
}

// ---------------------------------------------------------------------------
// Causal flash attention. Q pre-scaled by 1/8. 1024 blocks (XCD-chunked,
// heavy-first), 4 waves x 16 q-rows, KVBLK=64, dbuf LDS, XOR-swizzled K/V
// AND P (40KB LDS total -> 4 blocks/CU), full/diag tile split, defer-max
// (THR=8), row-sum via ones-MFMA, counted-vmcnt loop (T4).
__global__ __launch_bounds__(256) void attn_fwd(const u16* __restrict__ Q,
                                                const u16* __restrict__ K,
                                                const u16* __restrict__ Vt,
                                                u16* __restrict__ O) {
  __shared__ __align__(16) u16 Ks[2][64 * 64];
  __shared__ __align__(16) u16 Vs[2][64 * 64];
  __shared__ __align__(16) u16 Ps[4][16 * 64];  // XOR-swizzled, 8KB
  const int tid = threadIdx.x, l = tid & 63, w = tid >> 6;
  const int lr = l & 15, lg = l >> 4;
  const int bid = blockIdx.x;
  const int xcd = bid & 7, i = bid >> 3;  // i in [0,128)
  const int bh = xcd * 4 + (i >> 5);      // 4 heads per XCD
  const int qx = 31 - (i & 31);           // heavy first
  const int b = bh >> 4, h = bh & 15;
  const int q0w = qx * 64 + w * 16;

  const u16* Kb = K + (size_t)(b * S_) * D_ + h * DK_;
  const u16* Vb = Vt + (size_t)bh * DK_ * S_;

  bf16x8 aq[2];
  {
    const u16* qp = Q + (size_t)(b * S_ + q0w + lr) * D_ + h * DK_ + lg * 8;
    aq[0] = *(const bf16x8*)qp;
    aq[1] = *(const bf16x8*)(qp + 32);
  }
  f32x4 oacc[4] = {};
  float mrow[4], lrow[4];
#pragma unroll
  for (int t = 0; t < 4; ++t) { mrow[t] = -1e30f; lrow[t] = 0.f; }

  u16x8 ones_u;
#pragma unroll
  for (int j = 0; j < 8; ++j) ones_u[j] = 0x3F80;  // bf16 1.0
  const bf16x8 ones = __builtin_bit_cast(bf16x8, ones_u);

  const int ntiles = qx + 1;

  auto STAGE = [&](int bf, int t) {
#pragma unroll
    for (int inst = 0; inst < 2; ++inst) {
      const int s = (w * 2 + inst) * 64 + l;
      const int r = s >> 3, ch = s & 7;
      const int chs = ch ^ (r & 7);
      async_lds16(Kb + (size_t)(t * 64 + r) * D_ + chs * 8,
                  (char*)Ks[bf] + (w * 2 + inst) * 1024);
      async_lds16(Vb + (size_t)r * S_ + t * 64 + chs * 8,
                  (char*)Vs[bf] + (w * 2 + inst) * 1024);
    }
  };

  // P store: row r, col c (orig) -> Ps[w][r*64 + (c ^ ((r&7)*8))]
  auto PSTORE = [&](int r, int c, u16 v) {
    Ps[w][r * 64 + (c ^ ((r & 7) * 8))] = v;
  };

  STAGE(0, 0);
  int cur = 0;
  for (int it = 0; it < ntiles; ++it) {
    if (it + 1 < ntiles) {
      STAGE(cur ^ 1, it + 1);
      VMCNT_WAIT(4);  // tile-cur loads landed; next tile's 4 in flight
    } else {
      VMCNT_WAIT(0);
    }
    raw_barrier();
    // QK^T: S[16q][64kv]
    f32x4 sf[4];
    __builtin_amdgcn_s_setprio(1);
#pragma unroll
    for (int n = 0; n < 4; ++n) {
      const int kvr = n * 16 + lr;
      f32x4 z = {};
      bf16x8 bk0 = *(const bf16x8*)&Ks[cur][kvr * 64 + ((lg ^ (kvr & 7)) * 8)];
      bf16x8 bk1 =
          *(const bf16x8*)&Ks[cur][kvr * 64 + (((4 + lg) ^ (kvr & 7)) * 8)];
      z = __builtin_amdgcn_mfma_f32_16x16x32_bf16(aq[0], bk0, z, 0, 0, 0);
      z = __builtin_amdgcn_mfma_f32_16x16x32_bf16(aq[1], bk1, z, 0, 0, 0);
      sf[n] = z;
    }
    __builtin_amdgcn_s_setprio(0);
    if (it < qx) {  // FULL tile: no mask; defer-max
      float fm[4];
      bool exc = false;
#pragma unroll
      for (int t = 0; t < 4; ++t) {
        fm[t] = fmaxf(fmaxf(sf[0][t], sf[1][t]), fmaxf(sf[2][t], sf[3][t]));
        exc |= fm[t] > mrow[t] + 8.f;
      }
      if (__any(exc)) {
#pragma unroll
        for (int t = 0; t < 4; ++t) {
          float mx = fm[t];
#pragma unroll
          for (int off = 1; off < 16; off <<= 1)
            mx = fmaxf(mx, __shfl_xor(mx, off));
          const float nm = fmaxf(mrow[t], mx);
          const float c = __expf(mrow[t] - nm);
          mrow[t] = nm;
          lrow[t] *= c;
#pragma unroll
          for (int d = 0; d < 4; ++d) oacc[d][t] *= c;
        }
      }
#pragma unroll
      for (int t = 0; t < 4; ++t)
#pragma unroll
        for (int n = 0; n < 4; ++n)
          PSTORE(lg * 4 + t, n * 16 + lr, f2bf(__expf(sf[n][t] - mrow[t])));
    } else {  // DIAGONAL tile: causal mask + full reduce
      const int kv0 = it * 64;
#pragma unroll
      for (int t = 0; t < 4; ++t) {
        const int qrow = q0w + lg * 4 + t;
        float v[4];
#pragma unroll
        for (int n = 0; n < 4; ++n)
          v[n] = (kv0 + n * 16 + lr <= qrow) ? sf[n][t] : -1e30f;
        float mx = fmaxf(fmaxf(v[0], v[1]), fmaxf(v[2], v[3]));
#pragma unroll
        for (int off = 1; off < 16; off <<= 1)
          mx = fmaxf(mx, __shfl_xor(mx, off));
        const float nm = fmaxf(mrow[t], mx);
        const float c = __expf(mrow[t] - nm);
        mrow[t] = nm;
        lrow[t] *= c;
#pragma unroll
        for (int d = 0; d < 4; ++d) oacc[d][t] *= c;
#pragma unroll
        for (int n = 0; n < 4; ++n)
          PSTORE(lg * 4 + t, n * 16 + lr, f2bf(__expf(v[n] - nm)));
      }
    }
    // PV + row-sum (ones-MFMA). A-frag read: row lr, orig cols lg*8 / 32+lg*8
    bf16x8 ap0 = *(const bf16x8*)&Ps[w][lr * 64 + ((lg ^ (lr & 7)) * 8)];
    bf16x8 ap1 =
        *(const bf16x8*)&Ps[w][lr * 64 + (((4 + lg) ^ (lr & 7)) * 8)];
    __builtin_amdgcn_s_setprio(1);
    f32x4 zs = {};
    zs = __builtin_amdgcn_mfma_f32_16x16x32_bf16(ap0, ones, zs, 0, 0, 0);
    zs = __builtin_amdgcn_mfma_f32_16x16x32_bf16(ap1, ones, zs, 0, 0, 0);
#pragma unroll
    for (int d = 0; d < 4; ++d) {
      const int row = d * 16 + lr;
      bf16x8 bv0 = *(const bf16x8*)&Vs[cur][row * 64 + ((lg ^ (row & 7)) * 8)];
      bf16x8 bv1 =
          *(const bf16x8*)&Vs[cur][row * 64 + (((4 + lg) ^ (row & 7)) * 8)];
      oacc[d] = __builtin_amdgcn_mfma_f32_16x16x32_bf16(ap0, bv0, oacc[d], 0, 0, 0);
      oacc[d] = __builtin_amdgcn_mfma_f32_16x16x32_bf16(ap1, bv1, oacc[d], 0, 0, 0);
    }
    __builtin_amdgcn_s_setprio(0);
#pragma unroll
    for (int t = 0; t < 4; ++t) lrow[t] += zs[t];
    raw_barrier();  // compute done before next STAGE overwrites buf cur
    cur ^= 1;
  }
#pragma unroll
  for (int d = 0; d < 4; ++d) {
#pragma unroll
    for (int t = 0; t < 4; ++t) {
      const size_t idx =
          (size_t)(b * S_ + q0w + lg * 4 + t) * D_ + h * DK_ + d * 16 + lr;
      O[idx] = f2bf(oacc[d][t] / lrow[t]);
    }
  }
}

// ---------------------------------------------------------------------------
extern "C" void kernel_launch(void* const* d_in, const int* in_sizes, int n_in,
                              void* d_out, int out_size, void* d_ws,
                              size_t ws_size, hipStream_t stream) {
  (void)in_sizes; (void)n_in; (void)out_size; (void)ws_size;
  const float* x = (const float*)d_in[0];
  const float* wq = (const float*)d_in[1];
  const float* wk = (const float*)d_in[2];
  const float* wv = (const float*)d_in[3];
  const float* wo = (const float*)d_in[4];
  const float* w1 = (const float*)d_in[5];
  const float* w2 = (const float*)d_in[6];
  const float* w3 = (const float*)d_in[7];
  const float* g1 = (const float*)d_in[8];
  const float* g2 = (const float*)d_in[9];
  const int* tp = (const int*)d_in[10];
  float* out = (float*)d_out;

  char* ws = (char*)d_ws;
  const size_t MB = 1024u * 1024u;
  u16* wqkvb = (u16*)(ws + 0 * MB);   // [3072][1024] = 6MB
  u16* wob  = (u16*)(ws + 6 * MB);
  u16* wb13 = (u16*)(ws + 8 * MB);    // [8192][1024] block-interleaved = 16MB
  u16* w2b  = (u16*)(ws + 24 * MB);   // [1024][4096] = 8MB
  u16* hb   = (u16*)(ws + 32 * MB);   // rmsnorm1 out; later attn-out
  float* yb = (float*)(ws + 40 * MB); // 16MB f32
  u16* h2b  = (u16*)(ws + 56 * MB);
  u16* Qb   = (u16*)(ws + 64 * MB);   // Q; K at +8MB; Vt at +16MB (EPI3)
  u16* Kb   = (u16*)(ws + 72 * MB);
  u16* Vtb  = (u16*)(ws + 80 * MB);
  u16* ffb  = (u16*)(ws + 96 * MB);   // [4096][4096] = 32MB
  u16* aob  = hb;

  f2b_all<<<16384, 256, 0, stream>>>(wq, wk, wv, wo, w1, w2, w3, wqkvb, wob,
                                     wb13, w2b);

  rmsnorm_k<<<4096, 256, 0, stream>>>(x, g1, hb);

  // fused QKV projection + RoPE + V-transpose: N=3072, BN=192 -> 256 blocks,
  // regions 4n x 8m per XCD
  gemm8ph<3, 192, 4, 8><<<dim3(16, 16), 512, 0, stream>>>(
      hb, wqkvb, Qb, nullptr, 3072, 1024, tp);

  attn_fwd<<<1024, 256, 0, stream>>>(Qb, Kb, Vtb, aob);

  // WO: 128^2 tiles, BK=128, regions 4n x 8m per XCD
  gemm2ph<128, 128, 128, 1, 4, 8><<<dim3(8, 32), 512, 0, stream>>>(
      aob, wob, yb, x, 1024, 1024);
  rmsnorm_k<<<4096, 256, 0, stream>>>(yb, g2, h2b);

  // fused FF up-projection + SwiGLU: N=8192, regions 8n x 8m per XCD
  gemm8ph<4, 256, 8, 8><<<dim3(32, 16), 512, 0, stream>>>(
      h2b, wb13, ffb, nullptr, 8192, 1024, nullptr);
  // W2: 128^2 tiles, BK=128, regions 4n x 8m per XCD
  gemm2ph<128, 128, 128, 1, 4, 8><<<dim3(8, 32), 512, 0, stream>>>(
      ffb, w2b, out, yb, 1024, 4096);
}

// Round 18
// 266.194 us; speedup vs baseline: 1.0526x; 1.0170x over previous
//
#include <hip/hip_runtime.h>
#include <hip/hip_bf16.h>

#define B_ 2
#define S_ 2048
#define D_ 1024
#define H_ 16
#define DK_ 64
#define FF_ 4096
#define M_ (B_ * S_)  // 4096 rows

typedef unsigned short u16;
typedef __bf16 bf16x8 __attribute__((ext_vector_type(8)));
typedef float f32x4 __attribute__((ext_vector_type(4)));
typedef u16 u16x4 __attribute__((ext_vector_type(4)));
typedef u16 u16x8 __attribute__((ext_vector_type(8)));

__device__ __forceinline__ u16 f2bf(float f) {
  __bf16 b = (__bf16)f;
  return __builtin_bit_cast(u16, b);
}
__device__ __forceinline__ float bf2f(u16 u) {
  __bf16 b = __builtin_bit_cast(__bf16, u);
  return (float)b;
}

// async global->LDS, 16B per lane. LDS dest is wave-uniform base + lane*16.
__device__ __forceinline__ void async_lds16(const void* g, void* l) {
  __builtin_amdgcn_global_load_lds(
      (const __attribute__((address_space(1))) unsigned int*)g,
      (__attribute__((address_space(3))) unsigned int*)l, 16, 0, 0);
}

// raw barrier + counted vmcnt (T4): keep prefetch loads in flight across
// barriers instead of __syncthreads' vmcnt(0)+lgkmcnt(0) drain.
__device__ __forceinline__ void raw_barrier() {
  asm volatile("s_barrier" ::: "memory");
}
#define VMCNT_WAIT(n) asm volatile("s_waitcnt vmcnt(" #n ")" ::: "memory")

// ---------------------------------------------------------------------------
// All weights f32 -> bf16 in ONE dispatch. W1/W3 are 16-ROW-BLOCK interleaved
// into wb13 (fused FF GEMM: j-even frags = a, j-odd = gate, same lane).
__global__ __launch_bounds__(256) void f2b_all(
    const float* __restrict__ wq, const float* __restrict__ wk,
    const float* __restrict__ wv, const float* __restrict__ wo,
    const float* __restrict__ w1, const float* __restrict__ w2,
    const float* __restrict__ w3, u16* __restrict__ wqkvb,
    u16* __restrict__ wob, u16* __restrict__ wb13, u16* __restrict__ w2b) {
  int i4 = blockIdx.x * 256 + threadIdx.x;  // < 4M float4s
  const float* src;
  u16* dst;
  int off, oo;
  if (i4 < 262144) { src = wq; dst = wqkvb; off = i4; oo = off; }
  else if (i4 < 524288) { src = wk; dst = wqkvb + 1048576; off = i4 - 262144; oo = off; }
  else if (i4 < 786432) { src = wv; dst = wqkvb + 2097152; off = i4 - 524288; oo = off; }
  else if (i4 < 1048576) { src = wo; dst = wob; off = i4 - 786432; oo = off; }
  else if (i4 < 2097152) {  // w1 row r -> wb13 row (r>>4)*32 + (r&15)
    src = w1; dst = wb13; off = i4 - 1048576;
    const int r = off >> 8;
    oo = (((r >> 4) * 32) + (r & 15)) * 256 + (off & 255);
  } else if (i4 < 3145728) { src = w2; dst = w2b; off = i4 - 2097152; oo = off; }
  else {  // w3 row r -> wb13 row (r>>4)*32 + 16 + (r&15)
    src = w3; dst = wb13; off = i4 - 3145728;
    const int r = off >> 8;
    oo = (((r >> 4) * 32) + 16 + (r & 15)) * 256 + (off & 255);
  }
  float4 v = ((const float4*)src)[off];
  u16x4 o;
  o[0] = f2bf(v.x); o[1] = f2bf(v.y); o[2] = f2bf(v.z); o[3] = f2bf(v.w);
  *(u16x4*)(dst + (size_t)oo * 4) = o;
}

// ---------------------------------------------------------------------------
// RMSNorm: f32 [rows][1024] -> bf16, block per row, 256 threads * 4 cols
__global__ __launch_bounds__(256) void rmsnorm_k(const float* __restrict__ X,
                                                 const float* __restrict__ G,
                                                 u16* __restrict__ Out) {
  const int row = blockIdx.x, tid = threadIdx.x;
  const float4 xv = *(const float4*)(X + (size_t)row * D_ + tid * 4);
  float ss = xv.x * xv.x + xv.y * xv.y + xv.z * xv.z + xv.w * xv.w;
#pragma unroll
  for (int off = 1; off < 64; off <<= 1) ss += __shfl_xor(ss, off);
  __shared__ float red[4];
  if ((tid & 63) == 0) red[tid >> 6] = ss;
  __syncthreads();
  const float tot = red[0] + red[1] + red[2] + red[3];
  const float sc = rsqrtf(tot * (1.0f / D_) + 1e-5f);
  const float4 gv = *(const float4*)(G + tid * 4);
  u16x4 o;
  o[0] = f2bf(xv.x * sc * gv.x);
  o[1] = f2bf(xv.y * sc * gv.y);
  o[2] = f2bf(xv.z * sc * gv.z);
  o[3] = f2bf(xv.w * sc * gv.w);
  *(u16x4*)(Out + (size_t)row * D_ + tid * 4) = o;
}

// ---------------------------------------------------------------------------
// 2D XCD-region block mapping: each XCD (= id&7) owns a rectangular RGN x RGM
// tile region, so its A panels and B panels stay L2-resident.
// Requires nwg == 8*RGN*RGM, gx % RGN == 0.
template <int RGN, int RGM>
__device__ __forceinline__ void region_map(int id, int gx, int BM, int BN,
                                           int& m0, int& n0) {
  const int xcd = id & 7, j = id >> 3;
  const int rcols = gx / RGN;
  m0 = ((xcd / rcols) * RGM + j / RGN) * BM;
  n0 = ((xcd % rcols) * RGN + (j % RGN)) * BN;
}

// ---------------------------------------------------------------------------
// 8-phase-style 256xBN x64 GEMM (r15 schedule + r18 barrier diet):
// ALL prefetch loads issued in PHASE 0 (overlapped with compute issue);
// per-phase barriers reduced to TRAILING only (no inter-wave data hazard
// exists within a K-tile -- all waves only READ the current buffer; the
// trailing barrier alone keeps phase lockstep, drift <= 1 phase).
// Tile-end: vmcnt(0) (loads issued ~3.25 phases ago, L2-hit w/ region map)
// + barrier before buffer swap.
// EPI 0: bf16 store.
// EPI 3: fused QKV: Q,K RoPE via __shfl_xor pair rotation with INLINE
//        __sinf/__cosf (r7: pointer-output sincosf spills all acc VGPRs);
//        Q scaled 1/8; V stored transposed into Vt[32 bh][64 dk][2048 s].
// EPI 4: fused SwiGLU (16-row-block-interleaved wb13, per-lane, no shfl).
template <int EPI, int BN, int RGN, int RGM>
__global__ __launch_bounds__(512) void gemm8ph(const u16* __restrict__ A,
                                               const u16* __restrict__ Bw,
                                               void* __restrict__ Cout,
                                               const void* __restrict__ auxp,
                                               int N, int K,
                                               const int* __restrict__ tp) {
  constexpr int BM = 256, BK = 64;
  constexpr int CPR = BK / 8;          // 8 chunks per row
  constexpr int ACH = BM * CPR;        // 2048 A-chunks per K-tile
  constexpr int TCH = (BM + BN) * CPR; // total chunks per K-tile
  constexpr int NL = TCH / 512;        // loads per thread per K-tile
  constexpr int NR = BN / 64;          // B fragments per wave per kk
  __shared__ __align__(16) u16 As[2][BM * BK];
  __shared__ __align__(16) u16 Bs[2][BN * BK];
  const int tid = threadIdx.x, l = tid & 63, w = tid >> 6;
  const int gx = gridDim.x;
  const int id = blockIdx.y * gx + blockIdx.x;
  int m0, n0;
  region_map<RGN, RGM>(id, gx, BM, BN, m0, n0);
  const int wm = (w >> 2) * 128, wn = (w & 3) * (BN / 4);
  const int lr = l & 15, lg = l >> 4;

  f32x4 acc[8][NR] = {};

  auto STAGE_ALL = [&](int bf, int k0) {
#pragma unroll
    for (int i = 0; i < NL; ++i) {
      const int s = i * 512 + tid;
      const int base = i * 512 + w * 64;
      if (base < ACH) {
        const int r = s / CPR, ch = s % CPR;
        async_lds16(A + (size_t)(m0 + r) * K + k0 + ((ch ^ (r & 7)) * 8),
                    (char*)As[bf] + base * 16);
      } else {
        const int s2 = s - ACH;
        const int r = s2 / CPR, ch = s2 % CPR;
        async_lds16(Bw + (size_t)(n0 + r) * K + k0 + ((ch ^ (r & 7)) * 8),
                    (char*)Bs[bf] + (base - ACH) * 16);
      }
    }
  };

  STAGE_ALL(0, 0);
  VMCNT_WAIT(0);
  raw_barrier();
  int cur = 0;
  for (int k0 = 0; k0 < K; k0 += BK) {
    const bool more = (k0 + BK) < K;
    bf16x8 bfr[NR];
#pragma unroll
    for (int ph = 0; ph < 4; ++ph) {
      const int kk = ph >> 1, iq = ph & 1;
      if (iq == 0) {  // B-half read once per kk, reused by both i-quads
#pragma unroll
        for (int j = 0; j < NR; ++j) {
          const int row = wn + j * 16 + lr;
          bfr[j] = *(const bf16x8*)&Bs[cur][row * BK +
                                            (((kk * 4 + lg) ^ (row & 7)) * 8)];
        }
      }
      bf16x8 af[4];
#pragma unroll
      for (int i = 0; i < 4; ++i) {
        const int row = wm + (iq * 4 + i) * 16 + lr;
        af[i] = *(const bf16x8*)&As[cur][row * BK +
                                         (((kk * 4 + lg) ^ (row & 7)) * 8)];
      }
      // all prefetch issued in phase 0 -> overlapped with compute issue
      if (more && ph == 0) STAGE_ALL(cur ^ 1, k0 + BK);
      // (no pre-MFMA barrier: no intra-tile inter-wave hazard; trailing
      //  barrier below keeps lockstep)
      __builtin_amdgcn_s_setprio(1);
#pragma unroll
      for (int i = 0; i < 4; ++i)
#pragma unroll
        for (int j = 0; j < NR; ++j)
          acc[iq * 4 + i][j] = __builtin_amdgcn_mfma_f32_16x16x32_bf16(
              af[i], bfr[j], acc[iq * 4 + i][j], 0, 0, 0);
      __builtin_amdgcn_s_setprio(0);
      if (ph < 3) raw_barrier();
    }
    if (more) {
      VMCNT_WAIT(0);  // loads issued 3.25 phases ago; L2-hit w/ region map
      raw_barrier();  // tile-end: phase-3 reads consumed (lgkmcnt before
                      // MFMA, MFMA precedes barrier) -> buffer swap safe
    }
    cur ^= 1;
  }

  // epilogue: C/D layout col = l&15, row = (l>>4)*4 + t  [m89-verified]
  if (EPI == 0 || EPI == 4) {
#pragma unroll
    for (int i = 0; i < 8; ++i) {
#pragma unroll
      for (int j = 0; j < NR; ++j) {
#pragma unroll
        for (int t = 0; t < 4; ++t) {
          const int grow = m0 + wm + i * 16 + lg * 4 + t;
          const int gcol = n0 + wn + j * 16 + lr;
          const float v = acc[i][j][t];
          if (EPI == 0) {
            ((u16*)Cout)[(size_t)grow * N + gcol] = f2bf(v);
          } else {
            if (j & 1) continue;  // handled with pair j, j+1
            const float a = v, g = acc[i][j + 1][t];
            const float sw = a / (1.f + __expf(-a)) * g;
            const int ocol = ((n0 + wn) >> 1) + (j >> 1) * 16 + lr;
            ((u16*)Cout)[(size_t)grow * FF_ + ocol] = f2bf(sw);
          }
        }
      }
    }
  } else {  // EPI 3: QKV + RoPE + V-transpose. Region per j (16-col runs
            // never straddle a 1024 boundary).
#pragma unroll
    for (int i = 0; i < 8; ++i) {
      const int grow0 = m0 + wm + i * 16 + lg * 4;
      float posf[4];
#pragma unroll
      for (int t = 0; t < 4; ++t) posf[t] = (float)tp[grow0 + t];
      const int bb = grow0 >> 11, s0 = grow0 & 2047;
#pragma unroll
      for (int j = 0; j < NR; ++j) {
        const int gcol = n0 + wn + j * 16 + lr;
        const int region = gcol >> 10;  // wave-uniform within this j
        if (region < 2) {
          u16* dst = (u16*)Cout + (size_t)region * ((size_t)M_ * D_);
          const float qscale = (region == 0) ? 0.125f : 1.0f;
          const float invf = __expf(-(float)((gcol & 63) >> 1) *
                                    (9.210340371976184f / 32.0f));
          const float sgn = (gcol & 1) ? 1.f : -1.f;
#pragma unroll
          for (int t = 0; t < 4; ++t) {
            const float own = acc[i][j][t];
            const float pe = __shfl_xor(own, 1);
            const float ang = posf[t] * invf;
            const float sn = __sinf(ang), cs = __cosf(ang);
            dst[(size_t)(grow0 + t) * D_ + (gcol & 1023)] =
                f2bf((own * cs + sgn * pe * sn) * qscale);
          }
        } else {
          u16* vt = (u16*)Cout + 2 * ((size_t)M_ * D_);
          const int vcol = gcol & 1023;
          u16x4 pk;
#pragma unroll
          for (int t = 0; t < 4; ++t) pk[t] = f2bf(acc[i][j][t]);
          const size_t addr =
              ((size_t)(bb * 16 + (vcol >> 6)) * 64 + (vcol & 63)) * 2048 + s0;
          *(u16x4*)(vt + addr) = pk;
        }
      }
    }
  }
}

// ---------------------------------------------------------------------------
// 2-phase double-buffered GEMM with counted-vmcnt barriers (r9-proven), used
// for the N=1024 shapes (WO, W2) at 128x128 BK=128. EPI 1: f32 aux+acc store.
// NOTE: no libm calls with pointer outs (sincosf) in epilogues (r7 postmortem).
template <int BM, int BN, int BK, int EPI, int RGN, int RGM>
__global__ __launch_bounds__(512) void gemm2ph(const u16* __restrict__ A,
                                               const u16* __restrict__ Bw,
                                               void* __restrict__ Cout,
                                               const void* __restrict__ auxp,
                                               int N, int K) {
  constexpr int CPR = BK / 8;
  constexpr int ACH = BM * CPR;
  constexpr int TCH = (BM + BN) * CPR;
  constexpr int MR = BM / 32, NR = BN / 64;
  static_assert(TCH / 512 == 8, "vmcnt(8) assumes 8 loads/thread per STAGE");
  __shared__ __align__(16) u16 As[2][BM * BK];
  __shared__ __align__(16) u16 Bs[2][BN * BK];
  const int tid = threadIdx.x, l = tid & 63, w = tid >> 6;
  const int gx = gridDim.x;
  const int id = blockIdx.y * gx + blockIdx.x;
  int m0, n0;
  region_map<RGN, RGM>(id, gx, BM, BN, m0, n0);
  const int wm = (w >> 2) * (BM / 2), wn = (w & 3) * (BN / 4);
  const int lr = l & 15, lg = l >> 4;

  f32x4 acc[MR][NR] = {};

  auto STAGE = [&](int bf, int k0) {
#pragma unroll
    for (int i = 0; i < TCH / 512; ++i) {
      const int s = i * 512 + tid;
      const int base = i * 512 + w * 64;
      if (base < ACH) {
        const int r = s / CPR, ch = s % CPR;
        async_lds16(A + (size_t)(m0 + r) * K + k0 + ((ch ^ (r & 7)) * 8),
                    (char*)As[bf] + base * 16);
      } else {
        const int s2 = s - ACH;
        const int r = s2 / CPR, ch = s2 % CPR;
        async_lds16(Bw + (size_t)(n0 + r) * K + k0 + ((ch ^ (r & 7)) * 8),
                    (char*)Bs[bf] + (base - ACH) * 16);
      }
    }
  };

  STAGE(0, 0);
  int cur = 0;
  for (int k0 = 0; k0 < K; k0 += BK) {
    if (k0 + BK < K) {
      STAGE(cur ^ 1, k0 + BK);
      VMCNT_WAIT(8);
    } else {
      VMCNT_WAIT(0);
    }
    raw_barrier();
#pragma unroll
    for (int kk = 0; kk < BK / 32; ++kk) {
      bf16x8 af[MR], bfr[NR];
#pragma unroll
      for (int i = 0; i < MR; ++i) {
        const int row = wm + i * 16 + lr;
        af[i] = *(const bf16x8*)&As[cur][row * BK +
                                         (((kk * 4 + lg) ^ (row & 7)) * 8)];
      }
#pragma unroll
      for (int j = 0; j < NR; ++j) {
        const int row = wn + j * 16 + lr;
        bfr[j] = *(const bf16x8*)&Bs[cur][row * BK +
                                          (((kk * 4 + lg) ^ (row & 7)) * 8)];
      }
      __builtin_amdgcn_s_setprio(1);
#pragma unroll
      for (int i = 0; i < MR; ++i)
#pragma unroll
        for (int j = 0; j < NR; ++j)
          acc[i][j] = __builtin_amdgcn_mfma_f32_16x16x32_bf16(
              af[i], bfr[j], acc[i][j], 0, 0, 0);
      __builtin_amdgcn_s_setprio(0);
    }
    raw_barrier();
    cur ^= 1;
  }

#pragma unroll
  for (int i = 0; i < MR; ++i) {
#pragma unroll
    for (int j = 0; j < NR; ++j) {
#pragma unroll
      for (int t = 0; t < 4; ++t) {
        const int grow = m0 + wm + i * 16 + lg * 4 + t;
        const int gcol = n0 + wn + j * 16 + lr;
        const float v = acc[i][j][t];
        if (EPI == 0) {
          ((u16*)Cout)[(size_t)grow * N + gcol] = f2bf(v);
        } else if (EPI == 1) {
          const size_t idx = (size_t)grow * N + gcol;
          ((float*)Cout)[idx] = ((const float*)auxp)[idx] + v;
        }
      }
    }
  }
}

// ---------------------------------------------------------------------------
// Causal flash attention. Q pre-scaled by 1/8. 1024 blocks (XCD-chunked,
// heavy-first), 4 waves x 16 q-rows, KVBLK=64, dbuf LDS, XOR-swizzled K/V
// AND P (40KB LDS total -> 4 blocks/CU), full/diag tile split, defer-max
// (THR=8), row-sum via ones-MFMA, counted-vmcnt loop (T4).
__global__ __launch_bounds__(256) void attn_fwd(const u16* __restrict__ Q,
                                                const u16* __restrict__ K,
                                                const u16* __restrict__ Vt,
                                                u16* __restrict__ O) {
  __shared__ __align__(16) u16 Ks[2][64 * 64];
  __shared__ __align__(16) u16 Vs[2][64 * 64];
  __shared__ __align__(16) u16 Ps[4][16 * 64];  // XOR-swizzled, 8KB
  const int tid = threadIdx.x, l = tid & 63, w = tid >> 6;
  const int lr = l & 15, lg = l >> 4;
  const int bid = blockIdx.x;
  const int xcd = bid & 7, i = bid >> 3;  // i in [0,128)
  const int bh = xcd * 4 + (i >> 5);      // 4 heads per XCD
  const int qx = 31 - (i & 31);           // heavy first
  const int b = bh >> 4, h = bh & 15;
  const int q0w = qx * 64 + w * 16;

  const u16* Kb = K + (size_t)(b * S_) * D_ + h * DK_;
  const u16* Vb = Vt + (size_t)bh * DK_ * S_;

  bf16x8 aq[2];
  {
    const u16* qp = Q + (size_t)(b * S_ + q0w + lr) * D_ + h * DK_ + lg * 8;
    aq[0] = *(const bf16x8*)qp;
    aq[1] = *(const bf16x8*)(qp + 32);
  }
  f32x4 oacc[4] = {};
  float mrow[4], lrow[4];
#pragma unroll
  for (int t = 0; t < 4; ++t) { mrow[t] = -1e30f; lrow[t] = 0.f; }

  u16x8 ones_u;
#pragma unroll
  for (int j = 0; j < 8; ++j) ones_u[j] = 0x3F80;  // bf16 1.0
  const bf16x8 ones = __builtin_bit_cast(bf16x8, ones_u);

  const int ntiles = qx + 1;

  auto STAGE = [&](int bf, int t) {
#pragma unroll
    for (int inst = 0; inst < 2; ++inst) {
      const int s = (w * 2 + inst) * 64 + l;
      const int r = s >> 3, ch = s & 7;
      const int chs = ch ^ (r & 7);
      async_lds16(Kb + (size_t)(t * 64 + r) * D_ + chs * 8,
                  (char*)Ks[bf] + (w * 2 + inst) * 1024);
      async_lds16(Vb + (size_t)r * S_ + t * 64 + chs * 8,
                  (char*)Vs[bf] + (w * 2 + inst) * 1024);
    }
  };

  // P store: row r, col c (orig) -> Ps[w][r*64 + (c ^ ((r&7)*8))]
  auto PSTORE = [&](int r, int c, u16 v) {
    Ps[w][r * 64 + (c ^ ((r & 7) * 8))] = v;
  };

  STAGE(0, 0);
  int cur = 0;
  for (int it = 0; it < ntiles; ++it) {
    if (it + 1 < ntiles) {
      STAGE(cur ^ 1, it + 1);
      VMCNT_WAIT(4);  // tile-cur loads landed; next tile's 4 in flight
    } else {
      VMCNT_WAIT(0);
    }
    raw_barrier();
    // QK^T: S[16q][64kv]
    f32x4 sf[4];
    __builtin_amdgcn_s_setprio(1);
#pragma unroll
    for (int n = 0; n < 4; ++n) {
      const int kvr = n * 16 + lr;
      f32x4 z = {};
      bf16x8 bk0 = *(const bf16x8*)&Ks[cur][kvr * 64 + ((lg ^ (kvr & 7)) * 8)];
      bf16x8 bk1 =
          *(const bf16x8*)&Ks[cur][kvr * 64 + (((4 + lg) ^ (kvr & 7)) * 8)];
      z = __builtin_amdgcn_mfma_f32_16x16x32_bf16(aq[0], bk0, z, 0, 0, 0);
      z = __builtin_amdgcn_mfma_f32_16x16x32_bf16(aq[1], bk1, z, 0, 0, 0);
      sf[n] = z;
    }
    __builtin_amdgcn_s_setprio(0);
    if (it < qx) {  // FULL tile: no mask; defer-max
      float fm[4];
      bool exc = false;
#pragma unroll
      for (int t = 0; t < 4; ++t) {
        fm[t] = fmaxf(fmaxf(sf[0][t], sf[1][t]), fmaxf(sf[2][t], sf[3][t]));
        exc |= fm[t] > mrow[t] + 8.f;
      }
      if (__any(exc)) {
#pragma unroll
        for (int t = 0; t < 4; ++t) {
          float mx = fm[t];
#pragma unroll
          for (int off = 1; off < 16; off <<= 1)
            mx = fmaxf(mx, __shfl_xor(mx, off));
          const float nm = fmaxf(mrow[t], mx);
          const float c = __expf(mrow[t] - nm);
          mrow[t] = nm;
          lrow[t] *= c;
#pragma unroll
          for (int d = 0; d < 4; ++d) oacc[d][t] *= c;
        }
      }
#pragma unroll
      for (int t = 0; t < 4; ++t)
#pragma unroll
        for (int n = 0; n < 4; ++n)
          PSTORE(lg * 4 + t, n * 16 + lr, f2bf(__expf(sf[n][t] - mrow[t])));
    } else {  // DIAGONAL tile: causal mask + full reduce
      const int kv0 = it * 64;
#pragma unroll
      for (int t = 0; t < 4; ++t) {
        const int qrow = q0w + lg * 4 + t;
        float v[4];
#pragma unroll
        for (int n = 0; n < 4; ++n)
          v[n] = (kv0 + n * 16 + lr <= qrow) ? sf[n][t] : -1e30f;
        float mx = fmaxf(fmaxf(v[0], v[1]), fmaxf(v[2], v[3]));
#pragma unroll
        for (int off = 1; off < 16; off <<= 1)
          mx = fmaxf(mx, __shfl_xor(mx, off));
        const float nm = fmaxf(mrow[t], mx);
        const float c = __expf(mrow[t] - nm);
        mrow[t] = nm;
        lrow[t] *= c;
#pragma unroll
        for (int d = 0; d < 4; ++d) oacc[d][t] *= c;
#pragma unroll
        for (int n = 0; n < 4; ++n)
          PSTORE(lg * 4 + t, n * 16 + lr, f2bf(__expf(v[n] - nm)));
      }
    }
    // PV + row-sum (ones-MFMA). A-frag read: row lr, orig cols lg*8 / 32+lg*8
    bf16x8 ap0 = *(const bf16x8*)&Ps[w][lr * 64 + ((lg ^ (lr & 7)) * 8)];
    bf16x8 ap1 =
        *(const bf16x8*)&Ps[w][lr * 64 + (((4 + lg) ^ (lr & 7)) * 8)];
    __builtin_amdgcn_s_setprio(1);
    f32x4 zs = {};
    zs = __builtin_amdgcn_mfma_f32_16x16x32_bf16(ap0, ones, zs, 0, 0, 0);
    zs = __builtin_amdgcn_mfma_f32_16x16x32_bf16(ap1, ones, zs, 0, 0, 0);
#pragma unroll
    for (int d = 0; d < 4; ++d) {
      const int row = d * 16 + lr;
      bf16x8 bv0 = *(const bf16x8*)&Vs[cur][row * 64 + ((lg ^ (row & 7)) * 8)];
      bf16x8 bv1 =
          *(const bf16x8*)&Vs[cur][row * 64 + (((4 + lg) ^ (row & 7)) * 8)];
      oacc[d] = __builtin_amdgcn_mfma_f32_16x16x32_bf16(ap0, bv0, oacc[d], 0, 0, 0);
      oacc[d] = __builtin_amdgcn_mfma_f32_16x16x32_bf16(ap1, bv1, oacc[d], 0, 0, 0);
    }
    __builtin_amdgcn_s_setprio(0);
#pragma unroll
    for (int t = 0; t < 4; ++t) lrow[t] += zs[t];
    raw_barrier();  // compute done before next STAGE overwrites buf cur
    cur ^= 1;
  }
#pragma unroll
  for (int d = 0; d < 4; ++d) {
#pragma unroll
    for (int t = 0; t < 4; ++t) {
      const size_t idx =
          (size_t)(b * S_ + q0w + lg * 4 + t) * D_ + h * DK_ + d * 16 + lr;
      O[idx] = f2bf(oacc[d][t] / lrow[t]);
    }
  }
}

// ---------------------------------------------------------------------------
extern "C" void kernel_launch(void* const* d_in, const int* in_sizes, int n_in,
                              void* d_out, int out_size, void* d_ws,
                              size_t ws_size, hipStream_t stream) {
  (void)in_sizes; (void)n_in; (void)out_size; (void)ws_size;
  const float* x = (const float*)d_in[0];
  const float* wq = (const float*)d_in[1];
  const float* wk = (const float*)d_in[2];
  const float* wv = (const float*)d_in[3];
  const float* wo = (const float*)d_in[4];
  const float* w1 = (const float*)d_in[5];
  const float* w2 = (const float*)d_in[6];
  const float* w3 = (const float*)d_in[7];
  const float* g1 = (const float*)d_in[8];
  const float* g2 = (const float*)d_in[9];
  const int* tp = (const int*)d_in[10];
  float* out = (float*)d_out;

  char* ws = (char*)d_ws;
  const size_t MB = 1024u * 1024u;
  u16* wqkvb = (u16*)(ws + 0 * MB);   // [3072][1024] = 6MB
  u16* wob  = (u16*)(ws + 6 * MB);
  u16* wb13 = (u16*)(ws + 8 * MB);    // [8192][1024] block-interleaved = 16MB
  u16* w2b  = (u16*)(ws + 24 * MB);   // [1024][4096] = 8MB
  u16* hb   = (u16*)(ws + 32 * MB);   // rmsnorm1 out; later attn-out
  float* yb = (float*)(ws + 40 * MB); // 16MB f32
  u16* h2b  = (u16*)(ws + 56 * MB);
  u16* Qb   = (u16*)(ws + 64 * MB);   // Q; K at +8MB; Vt at +16MB (EPI3)
  u16* Kb   = (u16*)(ws + 72 * MB);
  u16* Vtb  = (u16*)(ws + 80 * MB);
  u16* ffb  = (u16*)(ws + 96 * MB);   // [4096][4096] = 32MB
  u16* aob  = hb;

  f2b_all<<<16384, 256, 0, stream>>>(wq, wk, wv, wo, w1, w2, w3, wqkvb, wob,
                                     wb13, w2b);

  rmsnorm_k<<<4096, 256, 0, stream>>>(x, g1, hb);

  // fused QKV projection + RoPE + V-transpose: N=3072, BN=192 -> 256 blocks,
  // regions 4n x 8m per XCD
  gemm8ph<3, 192, 4, 8><<<dim3(16, 16), 512, 0, stream>>>(
      hb, wqkvb, Qb, nullptr, 3072, 1024, tp);

  attn_fwd<<<1024, 256, 0, stream>>>(Qb, Kb, Vtb, aob);

  // WO: 128^2 tiles, BK=128, regions 4n x 8m per XCD
  gemm2ph<128, 128, 128, 1, 4, 8><<<dim3(8, 32), 512, 0, stream>>>(
      aob, wob, yb, x, 1024, 1024);
  rmsnorm_k<<<4096, 256, 0, stream>>>(yb, g2, h2b);

  // fused FF up-projection + SwiGLU: N=8192, regions 8n x 8m per XCD
  gemm8ph<4, 256, 8, 8><<<dim3(32, 16), 512, 0, stream>>>(
      h2b, wb13, ffb, nullptr, 8192, 1024, nullptr);
  // W2: 128^2 tiles, BK=128, regions 4n x 8m per XCD
  gemm2ph<128, 128, 128, 1, 4, 8><<<dim3(8, 32), 512, 0, stream>>>(
      ffb, w2b, out, yb, 1024, 4096);
}

// Round 19
// 262.477 us; speedup vs baseline: 1.0675x; 1.0142x over previous
//
#include <hip/hip_runtime.h>
#include <hip/hip_bf16.h>

#define B_ 2
#define S_ 2048
#define D_ 1024
#define H_ 16
#define DK_ 64
#define FF_ 4096
#define M_ (B_ * S_)  // 4096 rows

typedef unsigned short u16;
typedef __bf16 bf16x8 __attribute__((ext_vector_type(8)));
typedef float f32x4 __attribute__((ext_vector_type(4)));
typedef u16 u16x4 __attribute__((ext_vector_type(4)));
typedef u16 u16x8 __attribute__((ext_vector_type(8)));

__device__ __forceinline__ u16 f2bf(float f) {
  __bf16 b = (__bf16)f;
  return __builtin_bit_cast(u16, b);
}
__device__ __forceinline__ float bf2f(u16 u) {
  __bf16 b = __builtin_bit_cast(__bf16, u);
  return (float)b;
}

// async global->LDS, 16B per lane. LDS dest is wave-uniform base + lane*16.
__device__ __forceinline__ void async_lds16(const void* g, void* l) {
  __builtin_amdgcn_global_load_lds(
      (const __attribute__((address_space(1))) unsigned int*)g,
      (__attribute__((address_space(3))) unsigned int*)l, 16, 0, 0);
}

// raw barrier + counted vmcnt (T4): keep prefetch loads in flight across
// barriers instead of __syncthreads' vmcnt(0)+lgkmcnt(0) drain.
__device__ __forceinline__ void raw_barrier() {
  asm volatile("s_barrier" ::: "memory");
}
#define VMCNT_WAIT(n) asm volatile("s_waitcnt vmcnt(" #n ")" ::: "memory")

// ---------------------------------------------------------------------------
// All weights f32 -> bf16 in ONE dispatch. W1/W3 are 16-ROW-BLOCK interleaved
// into wb13 (fused FF GEMM: j-even frags = a, j-odd = gate, same lane).
__global__ __launch_bounds__(256) void f2b_all(
    const float* __restrict__ wq, const float* __restrict__ wk,
    const float* __restrict__ wv, const float* __restrict__ wo,
    const float* __restrict__ w1, const float* __restrict__ w2,
    const float* __restrict__ w3, u16* __restrict__ wqkvb,
    u16* __restrict__ wob, u16* __restrict__ wb13, u16* __restrict__ w2b) {
  int i4 = blockIdx.x * 256 + threadIdx.x;  // < 4M float4s
  const float* src;
  u16* dst;
  int off, oo;
  if (i4 < 262144) { src = wq; dst = wqkvb; off = i4; oo = off; }
  else if (i4 < 524288) { src = wk; dst = wqkvb + 1048576; off = i4 - 262144; oo = off; }
  else if (i4 < 786432) { src = wv; dst = wqkvb + 2097152; off = i4 - 524288; oo = off; }
  else if (i4 < 1048576) { src = wo; dst = wob; off = i4 - 786432; oo = off; }
  else if (i4 < 2097152) {  // w1 row r -> wb13 row (r>>4)*32 + (r&15)
    src = w1; dst = wb13; off = i4 - 1048576;
    const int r = off >> 8;
    oo = (((r >> 4) * 32) + (r & 15)) * 256 + (off & 255);
  } else if (i4 < 3145728) { src = w2; dst = w2b; off = i4 - 2097152; oo = off; }
  else {  // w3 row r -> wb13 row (r>>4)*32 + 16 + (r&15)
    src = w3; dst = wb13; off = i4 - 3145728;
    const int r = off >> 8;
    oo = (((r >> 4) * 32) + 16 + (r & 15)) * 256 + (off & 255);
  }
  float4 v = ((const float4*)src)[off];
  u16x4 o;
  o[0] = f2bf(v.x); o[1] = f2bf(v.y); o[2] = f2bf(v.z); o[3] = f2bf(v.w);
  *(u16x4*)(dst + (size_t)oo * 4) = o;
}

// ---------------------------------------------------------------------------
// RMSNorm: f32 [rows][1024] -> bf16, block per row, 256 threads * 4 cols
__global__ __launch_bounds__(256) void rmsnorm_k(const float* __restrict__ X,
                                                 const float* __restrict__ G,
                                                 u16* __restrict__ Out) {
  const int row = blockIdx.x, tid = threadIdx.x;
  const float4 xv = *(const float4*)(X + (size_t)row * D_ + tid * 4);
  float ss = xv.x * xv.x + xv.y * xv.y + xv.z * xv.z + xv.w * xv.w;
#pragma unroll
  for (int off = 1; off < 64; off <<= 1) ss += __shfl_xor(ss, off);
  __shared__ float red[4];
  if ((tid & 63) == 0) red[tid >> 6] = ss;
  __syncthreads();
  const float tot = red[0] + red[1] + red[2] + red[3];
  const float sc = rsqrtf(tot * (1.0f / D_) + 1e-5f);
  const float4 gv = *(const float4*)(G + tid * 4);
  u16x4 o;
  o[0] = f2bf(xv.x * sc * gv.x);
  o[1] = f2bf(xv.y * sc * gv.y);
  o[2] = f2bf(xv.z * sc * gv.z);
  o[3] = f2bf(xv.w * sc * gv.w);
  *(u16x4*)(Out + (size_t)row * D_ + tid * 4) = o;
}

// ---------------------------------------------------------------------------
// 2D XCD-region block mapping: each XCD (= id&7) owns a rectangular RGN x RGM
// tile region, so its A panels and B panels stay L2-resident.
// Requires nwg == 8*RGN*RGM, gx % RGN == 0.
template <int RGN, int RGM>
__device__ __forceinline__ void region_map(int id, int gx, int BM, int BN,
                                           int& m0, int& n0) {
  const int xcd = id & 7, j = id >> 3;
  const int rcols = gx / RGN;
  m0 = ((xcd / rcols) * RGM + j / RGN) * BM;
  n0 = ((xcd % rcols) * RGN + (j % RGN)) * BN;
}

// ---------------------------------------------------------------------------
// 256xBN x64 GEMM, ONE barrier + ONE vmcnt per K-tile (r19):
// r18 proved per-phase barriers are pure overhead (no intra-tile inter-wave
// hazard: all waves only READ the current buffer). r19 drops the remaining
// trailing per-phase barriers too; the single tile-end vmcnt(0)+barrier
// fully covers the buffer swap (each wave's ds_reads are register-consumed
// before it reaches the barrier; STAGE targets the other buffer).
// ALL prefetch loads issued early in the tile (overlapped with compute).
// EPI 0: bf16 store.
// EPI 3: fused QKV: Q,K RoPE via __shfl_xor pair rotation with INLINE
//        __sinf/__cosf (r7: pointer-output sincosf spills all acc VGPRs);
//        Q scaled 1/8; V stored transposed into Vt[32 bh][64 dk][2048 s].
// EPI 4: fused SwiGLU (16-row-block-interleaved wb13, per-lane, no shfl).
template <int EPI, int BN, int RGN, int RGM>
__global__ __launch_bounds__(512) void gemm8ph(const u16* __restrict__ A,
                                               const u16* __restrict__ Bw,
                                               void* __restrict__ Cout,
                                               const void* __restrict__ auxp,
                                               int N, int K,
                                               const int* __restrict__ tp) {
  constexpr int BM = 256, BK = 64;
  constexpr int CPR = BK / 8;          // 8 chunks per row
  constexpr int ACH = BM * CPR;        // 2048 A-chunks per K-tile
  constexpr int TCH = (BM + BN) * CPR; // total chunks per K-tile
  constexpr int NL = TCH / 512;        // loads per thread per K-tile
  constexpr int NR = BN / 64;          // B fragments per wave per kk
  __shared__ __align__(16) u16 As[2][BM * BK];
  __shared__ __align__(16) u16 Bs[2][BN * BK];
  const int tid = threadIdx.x, l = tid & 63, w = tid >> 6;
  const int gx = gridDim.x;
  const int id = blockIdx.y * gx + blockIdx.x;
  int m0, n0;
  region_map<RGN, RGM>(id, gx, BM, BN, m0, n0);
  const int wm = (w >> 2) * 128, wn = (w & 3) * (BN / 4);
  const int lr = l & 15, lg = l >> 4;

  f32x4 acc[8][NR] = {};

  auto STAGE_ALL = [&](int bf, int k0) {
#pragma unroll
    for (int i = 0; i < NL; ++i) {
      const int s = i * 512 + tid;
      const int base = i * 512 + w * 64;
      if (base < ACH) {
        const int r = s / CPR, ch = s % CPR;
        async_lds16(A + (size_t)(m0 + r) * K + k0 + ((ch ^ (r & 7)) * 8),
                    (char*)As[bf] + base * 16);
      } else {
        const int s2 = s - ACH;
        const int r = s2 / CPR, ch = s2 % CPR;
        async_lds16(Bw + (size_t)(n0 + r) * K + k0 + ((ch ^ (r & 7)) * 8),
                    (char*)Bs[bf] + (base - ACH) * 16);
      }
    }
  };

  STAGE_ALL(0, 0);
  VMCNT_WAIT(0);
  raw_barrier();
  int cur = 0;
  for (int k0 = 0; k0 < K; k0 += BK) {
    const bool more = (k0 + BK) < K;
    bf16x8 bfr[NR];
#pragma unroll
    for (int ph = 0; ph < 4; ++ph) {
      const int kk = ph >> 1, iq = ph & 1;
      if (iq == 0) {  // B-half read once per kk, reused by both i-quads
#pragma unroll
        for (int j = 0; j < NR; ++j) {
          const int row = wn + j * 16 + lr;
          bfr[j] = *(const bf16x8*)&Bs[cur][row * BK +
                                            (((kk * 4 + lg) ^ (row & 7)) * 8)];
        }
      }
      bf16x8 af[4];
#pragma unroll
      for (int i = 0; i < 4; ++i) {
        const int row = wm + (iq * 4 + i) * 16 + lr;
        af[i] = *(const bf16x8*)&As[cur][row * BK +
                                         (((kk * 4 + lg) ^ (row & 7)) * 8)];
      }
      // all prefetch issued in phase 0 -> overlapped with compute issue
      if (more && ph == 0) STAGE_ALL(cur ^ 1, k0 + BK);
      // (no per-phase barriers at all: no intra-tile inter-wave hazard;
      //  single tile-end barrier below covers the buffer swap)
      __builtin_amdgcn_s_setprio(1);
#pragma unroll
      for (int i = 0; i < 4; ++i)
#pragma unroll
        for (int j = 0; j < NR; ++j)
          acc[iq * 4 + i][j] = __builtin_amdgcn_mfma_f32_16x16x32_bf16(
              af[i], bfr[j], acc[iq * 4 + i][j], 0, 0, 0);
      __builtin_amdgcn_s_setprio(0);
    }
    if (more) {
      VMCNT_WAIT(0);  // prefetch issued ~1 tile of compute ago
      raw_barrier();  // tile-end: all waves' reads of cur consumed ->
                      // buffer swap safe
    }
    cur ^= 1;
  }

  // epilogue: C/D layout col = l&15, row = (l>>4)*4 + t  [m89-verified]
  if (EPI == 0 || EPI == 4) {
#pragma unroll
    for (int i = 0; i < 8; ++i) {
#pragma unroll
      for (int j = 0; j < NR; ++j) {
#pragma unroll
        for (int t = 0; t < 4; ++t) {
          const int grow = m0 + wm + i * 16 + lg * 4 + t;
          const int gcol = n0 + wn + j * 16 + lr;
          const float v = acc[i][j][t];
          if (EPI == 0) {
            ((u16*)Cout)[(size_t)grow * N + gcol] = f2bf(v);
          } else {
            if (j & 1) continue;  // handled with pair j, j+1
            const float a = v, g = acc[i][j + 1][t];
            const float sw = a / (1.f + __expf(-a)) * g;
            const int ocol = ((n0 + wn) >> 1) + (j >> 1) * 16 + lr;
            ((u16*)Cout)[(size_t)grow * FF_ + ocol] = f2bf(sw);
          }
        }
      }
    }
  } else {  // EPI 3: QKV + RoPE + V-transpose. Region per j (16-col runs
            // never straddle a 1024 boundary).
#pragma unroll
    for (int i = 0; i < 8; ++i) {
      const int grow0 = m0 + wm + i * 16 + lg * 4;
      float posf[4];
#pragma unroll
      for (int t = 0; t < 4; ++t) posf[t] = (float)tp[grow0 + t];
      const int bb = grow0 >> 11, s0 = grow0 & 2047;
#pragma unroll
      for (int j = 0; j < NR; ++j) {
        const int gcol = n0 + wn + j * 16 + lr;
        const int region = gcol >> 10;  // wave-uniform within this j
        if (region < 2) {
          u16* dst = (u16*)Cout + (size_t)region * ((size_t)M_ * D_);
          const float qscale = (region == 0) ? 0.125f : 1.0f;
          const float invf = __expf(-(float)((gcol & 63) >> 1) *
                                    (9.210340371976184f / 32.0f));
          const float sgn = (gcol & 1) ? 1.f : -1.f;
#pragma unroll
          for (int t = 0; t < 4; ++t) {
            const float own = acc[i][j][t];
            const float pe = __shfl_xor(own, 1);
            const float ang = posf[t] * invf;
            const float sn = __sinf(ang), cs = __cosf(ang);
            dst[(size_t)(grow0 + t) * D_ + (gcol & 1023)] =
                f2bf((own * cs + sgn * pe * sn) * qscale);
          }
        } else {
          u16* vt = (u16*)Cout + 2 * ((size_t)M_ * D_);
          const int vcol = gcol & 1023;
          u16x4 pk;
#pragma unroll
          for (int t = 0; t < 4; ++t) pk[t] = f2bf(acc[i][j][t]);
          const size_t addr =
              ((size_t)(bb * 16 + (vcol >> 6)) * 64 + (vcol & 63)) * 2048 + s0;
          *(u16x4*)(vt + addr) = pk;
        }
      }
    }
  }
}

// ---------------------------------------------------------------------------
// 2-phase double-buffered GEMM with counted-vmcnt barriers (r9-proven), used
// for the N=1024 shapes (WO, W2) at 128x128 BK=128. EPI 1: f32 aux+acc store.
// NOTE: no libm calls with pointer outs (sincosf) in epilogues (r7 postmortem).
template <int BM, int BN, int BK, int EPI, int RGN, int RGM>
__global__ __launch_bounds__(512) void gemm2ph(const u16* __restrict__ A,
                                               const u16* __restrict__ Bw,
                                               void* __restrict__ Cout,
                                               const void* __restrict__ auxp,
                                               int N, int K) {
  constexpr int CPR = BK / 8;
  constexpr int ACH = BM * CPR;
  constexpr int TCH = (BM + BN) * CPR;
  constexpr int MR = BM / 32, NR = BN / 64;
  static_assert(TCH / 512 == 8, "vmcnt(8) assumes 8 loads/thread per STAGE");
  __shared__ __align__(16) u16 As[2][BM * BK];
  __shared__ __align__(16) u16 Bs[2][BN * BK];
  const int tid = threadIdx.x, l = tid & 63, w = tid >> 6;
  const int gx = gridDim.x;
  const int id = blockIdx.y * gx + blockIdx.x;
  int m0, n0;
  region_map<RGN, RGM>(id, gx, BM, BN, m0, n0);
  const int wm = (w >> 2) * (BM / 2), wn = (w & 3) * (BN / 4);
  const int lr = l & 15, lg = l >> 4;

  f32x4 acc[MR][NR] = {};

  auto STAGE = [&](int bf, int k0) {
#pragma unroll
    for (int i = 0; i < TCH / 512; ++i) {
      const int s = i * 512 + tid;
      const int base = i * 512 + w * 64;
      if (base < ACH) {
        const int r = s / CPR, ch = s % CPR;
        async_lds16(A + (size_t)(m0 + r) * K + k0 + ((ch ^ (r & 7)) * 8),
                    (char*)As[bf] + base * 16);
      } else {
        const int s2 = s - ACH;
        const int r = s2 / CPR, ch = s2 % CPR;
        async_lds16(Bw + (size_t)(n0 + r) * K + k0 + ((ch ^ (r & 7)) * 8),
                    (char*)Bs[bf] + (base - ACH) * 16);
      }
    }
  };

  STAGE(0, 0);
  int cur = 0;
  for (int k0 = 0; k0 < K; k0 += BK) {
    if (k0 + BK < K) {
      STAGE(cur ^ 1, k0 + BK);
      VMCNT_WAIT(8);
    } else {
      VMCNT_WAIT(0);
    }
    raw_barrier();
#pragma unroll
    for (int kk = 0; kk < BK / 32; ++kk) {
      bf16x8 af[MR], bfr[NR];
#pragma unroll
      for (int i = 0; i < MR; ++i) {
        const int row = wm + i * 16 + lr;
        af[i] = *(const bf16x8*)&As[cur][row * BK +
                                         (((kk * 4 + lg) ^ (row & 7)) * 8)];
      }
#pragma unroll
      for (int j = 0; j < NR; ++j) {
        const int row = wn + j * 16 + lr;
        bfr[j] = *(const bf16x8*)&Bs[cur][row * BK +
                                          (((kk * 4 + lg) ^ (row & 7)) * 8)];
      }
      __builtin_amdgcn_s_setprio(1);
#pragma unroll
      for (int i = 0; i < MR; ++i)
#pragma unroll
        for (int j = 0; j < NR; ++j)
          acc[i][j] = __builtin_amdgcn_mfma_f32_16x16x32_bf16(
              af[i], bfr[j], acc[i][j], 0, 0, 0);
      __builtin_amdgcn_s_setprio(0);
    }
    raw_barrier();
    cur ^= 1;
  }

#pragma unroll
  for (int i = 0; i < MR; ++i) {
#pragma unroll
    for (int j = 0; j < NR; ++j) {
#pragma unroll
      for (int t = 0; t < 4; ++t) {
        const int grow = m0 + wm + i * 16 + lg * 4 + t;
        const int gcol = n0 + wn + j * 16 + lr;
        const float v = acc[i][j][t];
        if (EPI == 0) {
          ((u16*)Cout)[(size_t)grow * N + gcol] = f2bf(v);
        } else if (EPI == 1) {
          const size_t idx = (size_t)grow * N + gcol;
          ((float*)Cout)[idx] = ((const float*)auxp)[idx] + v;
        }
      }
    }
  }
}

// ---------------------------------------------------------------------------
// Causal flash attention. Q pre-scaled by 1/8. 1024 blocks (XCD-chunked,
// heavy-first), 4 waves x 16 q-rows, KVBLK=64, dbuf LDS, XOR-swizzled K/V
// AND P (40KB LDS total -> 4 blocks/CU), full/diag tile split, defer-max
// (THR=8), row-sum via ones-MFMA, counted-vmcnt loop (T4).
__global__ __launch_bounds__(256) void attn_fwd(const u16* __restrict__ Q,
                                                const u16* __restrict__ K,
                                                const u16* __restrict__ Vt,
                                                u16* __restrict__ O) {
  __shared__ __align__(16) u16 Ks[2][64 * 64];
  __shared__ __align__(16) u16 Vs[2][64 * 64];
  __shared__ __align__(16) u16 Ps[4][16 * 64];  // XOR-swizzled, 8KB
  const int tid = threadIdx.x, l = tid & 63, w = tid >> 6;
  const int lr = l & 15, lg = l >> 4;
  const int bid = blockIdx.x;
  const int xcd = bid & 7, i = bid >> 3;  // i in [0,128)
  const int bh = xcd * 4 + (i >> 5);      // 4 heads per XCD
  const int qx = 31 - (i & 31);           // heavy first
  const int b = bh >> 4, h = bh & 15;
  const int q0w = qx * 64 + w * 16;

  const u16* Kb = K + (size_t)(b * S_) * D_ + h * DK_;
  const u16* Vb = Vt + (size_t)bh * DK_ * S_;

  bf16x8 aq[2];
  {
    const u16* qp = Q + (size_t)(b * S_ + q0w + lr) * D_ + h * DK_ + lg * 8;
    aq[0] = *(const bf16x8*)qp;
    aq[1] = *(const bf16x8*)(qp + 32);
  }
  f32x4 oacc[4] = {};
  float mrow[4], lrow[4];
#pragma unroll
  for (int t = 0; t < 4; ++t) { mrow[t] = -1e30f; lrow[t] = 0.f; }

  u16x8 ones_u;
#pragma unroll
  for (int j = 0; j < 8; ++j) ones_u[j] = 0x3F80;  // bf16 1.0
  const bf16x8 ones = __builtin_bit_cast(bf16x8, ones_u);

  const int ntiles = qx + 1;

  auto STAGE = [&](int bf, int t) {
#pragma unroll
    for (int inst = 0; inst < 2; ++inst) {
      const int s = (w * 2 + inst) * 64 + l;
      const int r = s >> 3, ch = s & 7;
      const int chs = ch ^ (r & 7);
      async_lds16(Kb + (size_t)(t * 64 + r) * D_ + chs * 8,
                  (char*)Ks[bf] + (w * 2 + inst) * 1024);
      async_lds16(Vb + (size_t)r * S_ + t * 64 + chs * 8,
                  (char*)Vs[bf] + (w * 2 + inst) * 1024);
    }
  };

  // P store: row r, col c (orig) -> Ps[w][r*64 + (c ^ ((r&7)*8))]
  auto PSTORE = [&](int r, int c, u16 v) {
    Ps[w][r * 64 + (c ^ ((r & 7) * 8))] = v;
  };

  STAGE(0, 0);
  int cur = 0;
  for (int it = 0; it < ntiles; ++it) {
    if (it + 1 < ntiles) {
      STAGE(cur ^ 1, it + 1);
      VMCNT_WAIT(4);  // tile-cur loads landed; next tile's 4 in flight
    } else {
      VMCNT_WAIT(0);
    }
    raw_barrier();
    // QK^T: S[16q][64kv]
    f32x4 sf[4];
    __builtin_amdgcn_s_setprio(1);
#pragma unroll
    for (int n = 0; n < 4; ++n) {
      const int kvr = n * 16 + lr;
      f32x4 z = {};
      bf16x8 bk0 = *(const bf16x8*)&Ks[cur][kvr * 64 + ((lg ^ (kvr & 7)) * 8)];
      bf16x8 bk1 =
          *(const bf16x8*)&Ks[cur][kvr * 64 + (((4 + lg) ^ (kvr & 7)) * 8)];
      z = __builtin_amdgcn_mfma_f32_16x16x32_bf16(aq[0], bk0, z, 0, 0, 0);
      z = __builtin_amdgcn_mfma_f32_16x16x32_bf16(aq[1], bk1, z, 0, 0, 0);
      sf[n] = z;
    }
    __builtin_amdgcn_s_setprio(0);
    if (it < qx) {  // FULL tile: no mask; defer-max
      float fm[4];
      bool exc = false;
#pragma unroll
      for (int t = 0; t < 4; ++t) {
        fm[t] = fmaxf(fmaxf(sf[0][t], sf[1][t]), fmaxf(sf[2][t], sf[3][t]));
        exc |= fm[t] > mrow[t] + 8.f;
      }
      if (__any(exc)) {
#pragma unroll
        for (int t = 0; t < 4; ++t) {
          float mx = fm[t];
#pragma unroll
          for (int off = 1; off < 16; off <<= 1)
            mx = fmaxf(mx, __shfl_xor(mx, off));
          const float nm = fmaxf(mrow[t], mx);
          const float c = __expf(mrow[t] - nm);
          mrow[t] = nm;
          lrow[t] *= c;
#pragma unroll
          for (int d = 0; d < 4; ++d) oacc[d][t] *= c;
        }
      }
#pragma unroll
      for (int t = 0; t < 4; ++t)
#pragma unroll
        for (int n = 0; n < 4; ++n)
          PSTORE(lg * 4 + t, n * 16 + lr, f2bf(__expf(sf[n][t] - mrow[t])));
    } else {  // DIAGONAL tile: causal mask + full reduce
      const int kv0 = it * 64;
#pragma unroll
      for (int t = 0; t < 4; ++t) {
        const int qrow = q0w + lg * 4 + t;
        float v[4];
#pragma unroll
        for (int n = 0; n < 4; ++n)
          v[n] = (kv0 + n * 16 + lr <= qrow) ? sf[n][t] : -1e30f;
        float mx = fmaxf(fmaxf(v[0], v[1]), fmaxf(v[2], v[3]));
#pragma unroll
        for (int off = 1; off < 16; off <<= 1)
          mx = fmaxf(mx, __shfl_xor(mx, off));
        const float nm = fmaxf(mrow[t], mx);
        const float c = __expf(mrow[t] - nm);
        mrow[t] = nm;
        lrow[t] *= c;
#pragma unroll
        for (int d = 0; d < 4; ++d) oacc[d][t] *= c;
#pragma unroll
        for (int n = 0; n < 4; ++n)
          PSTORE(lg * 4 + t, n * 16 + lr, f2bf(__expf(v[n] - nm)));
      }
    }
    // PV + row-sum (ones-MFMA). A-frag read: row lr, orig cols lg*8 / 32+lg*8
    bf16x8 ap0 = *(const bf16x8*)&Ps[w][lr * 64 + ((lg ^ (lr & 7)) * 8)];
    bf16x8 ap1 =
        *(const bf16x8*)&Ps[w][lr * 64 + (((4 + lg) ^ (lr & 7)) * 8)];
    __builtin_amdgcn_s_setprio(1);
    f32x4 zs = {};
    zs = __builtin_amdgcn_mfma_f32_16x16x32_bf16(ap0, ones, zs, 0, 0, 0);
    zs = __builtin_amdgcn_mfma_f32_16x16x32_bf16(ap1, ones, zs, 0, 0, 0);
#pragma unroll
    for (int d = 0; d < 4; ++d) {
      const int row = d * 16 + lr;
      bf16x8 bv0 = *(const bf16x8*)&Vs[cur][row * 64 + ((lg ^ (row & 7)) * 8)];
      bf16x8 bv1 =
          *(const bf16x8*)&Vs[cur][row * 64 + (((4 + lg) ^ (row & 7)) * 8)];
      oacc[d] = __builtin_amdgcn_mfma_f32_16x16x32_bf16(ap0, bv0, oacc[d], 0, 0, 0);
      oacc[d] = __builtin_amdgcn_mfma_f32_16x16x32_bf16(ap1, bv1, oacc[d], 0, 0, 0);
    }
    __builtin_amdgcn_s_setprio(0);
#pragma unroll
    for (int t = 0; t < 4; ++t) lrow[t] += zs[t];
    raw_barrier();  // compute done before next STAGE overwrites buf cur
    cur ^= 1;
  }
#pragma unroll
  for (int d = 0; d < 4; ++d) {
#pragma unroll
    for (int t = 0; t < 4; ++t) {
      const size_t idx =
          (size_t)(b * S_ + q0w + lg * 4 + t) * D_ + h * DK_ + d * 16 + lr;
      O[idx] = f2bf(oacc[d][t] / lrow[t]);
    }
  }
}

// ---------------------------------------------------------------------------
extern "C" void kernel_launch(void* const* d_in, const int* in_sizes, int n_in,
                              void* d_out, int out_size, void* d_ws,
                              size_t ws_size, hipStream_t stream) {
  (void)in_sizes; (void)n_in; (void)out_size; (void)ws_size;
  const float* x = (const float*)d_in[0];
  const float* wq = (const float*)d_in[1];
  const float* wk = (const float*)d_in[2];
  const float* wv = (const float*)d_in[3];
  const float* wo = (const float*)d_in[4];
  const float* w1 = (const float*)d_in[5];
  const float* w2 = (const float*)d_in[6];
  const float* w3 = (const float*)d_in[7];
  const float* g1 = (const float*)d_in[8];
  const float* g2 = (const float*)d_in[9];
  const int* tp = (const int*)d_in[10];
  float* out = (float*)d_out;

  char* ws = (char*)d_ws;
  const size_t MB = 1024u * 1024u;
  u16* wqkvb = (u16*)(ws + 0 * MB);   // [3072][1024] = 6MB
  u16* wob  = (u16*)(ws + 6 * MB);
  u16* wb13 = (u16*)(ws + 8 * MB);    // [8192][1024] block-interleaved = 16MB
  u16* w2b  = (u16*)(ws + 24 * MB);   // [1024][4096] = 8MB
  u16* hb   = (u16*)(ws + 32 * MB);   // rmsnorm1 out; later attn-out
  float* yb = (float*)(ws + 40 * MB); // 16MB f32
  u16* h2b  = (u16*)(ws + 56 * MB);
  u16* Qb   = (u16*)(ws + 64 * MB);   // Q; K at +8MB; Vt at +16MB (EPI3)
  u16* Kb   = (u16*)(ws + 72 * MB);
  u16* Vtb  = (u16*)(ws + 80 * MB);
  u16* ffb  = (u16*)(ws + 96 * MB);   // [4096][4096] = 32MB
  u16* aob  = hb;

  f2b_all<<<16384, 256, 0, stream>>>(wq, wk, wv, wo, w1, w2, w3, wqkvb, wob,
                                     wb13, w2b);

  rmsnorm_k<<<4096, 256, 0, stream>>>(x, g1, hb);

  // fused QKV projection + RoPE + V-transpose: N=3072, BN=192 -> 256 blocks,
  // regions 4n x 8m per XCD
  gemm8ph<3, 192, 4, 8><<<dim3(16, 16), 512, 0, stream>>>(
      hb, wqkvb, Qb, nullptr, 3072, 1024, tp);

  attn_fwd<<<1024, 256, 0, stream>>>(Qb, Kb, Vtb, aob);

  // WO: 128^2 tiles, BK=128, regions 4n x 8m per XCD
  gemm2ph<128, 128, 128, 1, 4, 8><<<dim3(8, 32), 512, 0, stream>>>(
      aob, wob, yb, x, 1024, 1024);
  rmsnorm_k<<<4096, 256, 0, stream>>>(yb, g2, h2b);

  // fused FF up-projection + SwiGLU: N=8192, regions 8n x 8m per XCD
  gemm8ph<4, 256, 8, 8><<<dim3(32, 16), 512, 0, stream>>>(
      h2b, wb13, ffb, nullptr, 8192, 1024, nullptr);
  // W2: 128^2 tiles, BK=128, regions 4n x 8m per XCD
  gemm2ph<128, 128, 128, 1, 4, 8><<<dim3(8, 32), 512, 0, stream>>>(
      ffb, w2b, out, yb, 1024, 4096);
}